// Round 9
// baseline (8067.751 us; speedup 1.0000x reference)
//
#include <hip/hip_runtime.h>

#define NH 128
#define PD 64
#define NSD 128
#define NG 8
#define CHK 128
#define HIDD 4096
#define INTER_D 8192
#define CONV_D 10240
#define PROJ_D 18560
#define SEQ 2048
#define ROWS 4096
#define NCH 16

typedef __attribute__((ext_vector_type(8))) short bf16x8;
typedef __attribute__((ext_vector_type(4))) float f32x4;

__device__ __forceinline__ unsigned short f2bf(float f) {
  unsigned int u = __float_as_uint(f);
  u += 0x7FFF + ((u >> 16) & 1);
  return (unsigned short)(u >> 16);
}
__device__ __forceinline__ float bf2f(unsigned short s) {
  return __uint_as_float(((unsigned int)s) << 16);
}

__device__ __forceinline__ void gld16(const unsigned short* g, unsigned short* l) {
  __builtin_amdgcn_global_load_lds(
      (__attribute__((address_space(1))) const void*)g,
      (__attribute__((address_space(3))) void*)l, 16, 0, 0);
}

#define BAR() __builtin_amdgcn_s_barrier()
#define SCHED() __builtin_amdgcn_sched_barrier(0)
#define VMCNT(n) asm volatile("s_waitcnt vmcnt(" #n ")" ::: "memory")

// BK=64 legacy swizzled read (used by non-GEMM kernels' [128][64] tiles): kept for e-kernels
__device__ __forceinline__ bf16x8 ldsfrag(const unsigned short* slot, int row, int kslot) {
  int byte = row * 128 + (((kslot ^ (row & 7)) << 4));
  return *(const bf16x8*)((const char*)slot + byte);
}

// BK=32 half-tile: 8KB, stored as [64 row-pairs][128B], XOR-swizzled (proven geometry).
// logical (row in 0..127, fog in 0..3): rp=row>>1, granule g=(row&1)*4+fog, slot16 s=g^(rp&7)
__device__ __forceinline__ bf16x8 ldsfrag32(const unsigned short* slot, int row, int fog) {
  int rp = row >> 1;
  int s = (((row & 1) << 2) | fog) ^ (rp & 7);
  return *(const bf16x8*)((const char*)slot + rp * 128 + (s << 4));
}

// ---------------- f32 -> bf16 convert ----------------
__global__ __launch_bounds__(256) void cvt_kernel(const float* __restrict__ in,
                                                  unsigned short* __restrict__ out,
                                                  size_t n) {
  size_t i = ((size_t)blockIdx.x * 256 + threadIdx.x) * 4;
  if (i < n) {
    float4 f = *(const float4*)(in + i);
    ushort4 o;
    o.x = f2bf(f.x); o.y = f2bf(f.y); o.z = f2bf(f.z); o.w = f2bf(f.w);
    *(ushort4*)(out + i) = o;
  }
}

// ---------------- 256^2 4-phase GEMM, BK=32, 64KB LDS -> 2 blocks/CU ----------------
// 8 waves (2M x 4N). R3-proven phase/wait choreography re-derived for 1-load halves:
// prologue vmcnt(1); P1-end vmcnt(2); P4-end vmcnt(1). Stages always to opposite buffer.
template <int OUT_BF16>
__global__ __launch_bounds__(512, 4) void gemm256(const unsigned short* __restrict__ A,
                                                  const unsigned short* __restrict__ B,
                                                  unsigned short* __restrict__ outb,
                                                  float* __restrict__ outf,
                                                  int Nreal, int Ks, int Kl, int koff) {
  __shared__ unsigned short lds[8][4096];  // 8 half-slots x 8KB = 64KB
  int tid = threadIdx.x, l = tid & 63, w = tid >> 6;
  int wm = w >> 2, wn = w & 3;
  int il = l & 15, fog = l >> 4;  // fog in 0..3
  int bid = blockIdx.x;
  int xcd = bid & 7, local = bid >> 3;
  int mt = xcd * 2 + (local & 1), nt = local >> 1;
  const unsigned short* Abase = A + (size_t)mt * 256 * Ks + koff;
  const unsigned short* Bbase = B + (size_t)nt * 256 * Ks + koff;
  int NT = Kl >> 5;

  f32x4 acc[2][2][4][2];
#pragma unroll
  for (int a = 0; a < 2; ++a)
#pragma unroll
    for (int b = 0; b < 2; ++b)
#pragma unroll
      for (int m = 0; m < 4; ++m)
#pragma unroll
        for (int n = 0; n < 2; ++n) acc[a][b][m][n] = (f32x4){0.f, 0.f, 0.f, 0.f};

  // per-lane inverse-swizzled global source for linear gld16 dest
  int gg = (l & 7) ^ ((l >> 3) & 7);
  int grow_l = ((w * 8 + (l >> 3)) << 1) | (gg >> 2);  // 0..127
  int gcol_l = (gg & 3) * 8;                           // ushort offset in 0..24

  // stage half-tile ty (0:A0 1:B0 2:A1 3:B1) of k-tile tt; ONE gld16 per thread
  auto STG = [&](int tt, int ty) {
    int tc = tt < NT ? tt : NT - 1;
    const unsigned short* g = ((ty & 1) ? Bbase : Abase) + (size_t)((ty >> 1) * 128) * Ks + tc * 32;
    unsigned short* sp = (unsigned short*)lds[(tt & 1) * 4 + ty] + w * 512;  // wave-uniform
    gld16(g + (size_t)grow_l * Ks + gcol_l, sp);
  };

#define LDA(SLOT)                                          \
  _Pragma("unroll") for (int mi = 0; mi < 4; ++mi)         \
      av[mi] = ldsfrag32(SLOT, wm * 64 + mi * 16 + il, fog);
#define LDB(QN, SLOT)                                      \
  _Pragma("unroll") for (int ni = 0; ni < 2; ++ni)         \
      bv[QN][ni] = ldsfrag32(SLOT, wn * 32 + ni * 16 + il, fog);
#define MFMA_PH(QM, QN)                                    \
  _Pragma("unroll") for (int mi = 0; mi < 4; ++mi)         \
  _Pragma("unroll") for (int ni = 0; ni < 2; ++ni)         \
      acc[QM][QN][mi][ni] = __builtin_amdgcn_mfma_f32_16x16x32_bf16( \
          av[mi], bv[QN][ni], acc[QM][QN][mi][ni], 0, 0, 0);

  // prologue: tile0 all 4 halves; leave A1 (issued last) in flight
  STG(0, 0); STG(0, 1); STG(0, 3); STG(0, 2);
  VMCNT(1);
  BAR(); SCHED();

  for (int t = 0; t < NT; ++t) {
    const unsigned short* sA0 = lds[(t & 1) * 4 + 0];
    const unsigned short* sB0 = lds[(t & 1) * 4 + 1];
    const unsigned short* sA1 = lds[(t & 1) * 4 + 2];
    const unsigned short* sB1 = lds[(t & 1) * 4 + 3];
    bf16x8 av[4], bv[2][2];
    // P1: read A0 + both B quadrants; stage A0,B0 of t+1
    LDA(sA0); LDB(0, sB0); LDB(1, sB1);
    STG(t + 1, 0); STG(t + 1, 1);
    BAR();
    __builtin_amdgcn_s_setprio(1);
    MFMA_PH(0, 0);
    __builtin_amdgcn_s_setprio(0);
    VMCNT(2);  // A1(t) landed -> safe for P3 reads
    BAR(); SCHED();
    // P2: pure MFMA; stage B1 of t+1
    STG(t + 1, 3);
    __builtin_amdgcn_s_setprio(1);
    MFMA_PH(0, 1);
    __builtin_amdgcn_s_setprio(0);
    BAR();
    // P3: read A1; stage A1 of t+1
    LDA(sA1);
    STG(t + 1, 2);
    BAR();
    __builtin_amdgcn_s_setprio(1);
    MFMA_PH(1, 0);
    __builtin_amdgcn_s_setprio(0);
    BAR();
    // P4: pure MFMA
    __builtin_amdgcn_s_setprio(1);
    MFMA_PH(1, 1);
    __builtin_amdgcn_s_setprio(0);
    VMCNT(1);  // A0,B0,B1(t+1) landed -> safe for next P1 reads
    BAR(); SCHED();
  }
  VMCNT(0);

  // epilogue: C write
  int rl = (l >> 4) * 4;
#pragma unroll
  for (int qm = 0; qm < 2; ++qm)
#pragma unroll
    for (int qn = 0; qn < 2; ++qn)
#pragma unroll
      for (int mi = 0; mi < 4; ++mi)
#pragma unroll
        for (int ni = 0; ni < 2; ++ni) {
          int grow = mt * 256 + qm * 128 + wm * 64 + mi * 16 + rl;
          int gcol = nt * 256 + qn * 128 + wn * 32 + ni * 16 + il;
          if (!OUT_BF16 || gcol < Nreal) {
#pragma unroll
            for (int r = 0; r < 4; ++r) {
              float v = acc[qm][qn][mi][ni][r];
              if (OUT_BF16)
                outb[(size_t)(grow + r) * Nreal + gcol] = f2bf(v);
              else
                outf[(size_t)(grow + r) * Nreal + gcol] = v;
            }
          }
        }
#undef LDA
#undef LDB
#undef MFMA_PH
}

// ---------------- dt softplus + A*dt cumsum ----------------
__global__ __launch_bounds__(128) void dts_kernel(const unsigned short* __restrict__ proj,
                                                  const float* __restrict__ dt_bias,
                                                  const float* __restrict__ A_log,
                                                  float* __restrict__ dtg,
                                                  float* __restrict__ acsg) {
  int bc = blockIdx.x;
  int h = threadIdx.x;
  int b = bc >> 4, c = bc & 15;
  float A = -__expf(A_log[h]);
  float bias = dt_bias[h];
  float cum = 0.f;
  int row0 = b * SEQ + c * CHK;
#pragma unroll 4
  for (int ll = 0; ll < CHK; ++ll) {
    float x = bf2f(proj[(size_t)(row0 + ll) * PROJ_D + (PROJ_D - NH) + h]) + bias;
    float d = (x > 20.f) ? x : log1pf(expf(x));
    dtg[(size_t)(row0 + ll) * NH + h] = d;
    cum += A * d;
    acsg[(((size_t)bc * NH) + h) * CHK + ll] = cum;
  }
}

// ---------------- causal depthwise conv + bias + silu ----------------
__global__ __launch_bounds__(256) void conv_kernel(const unsigned short* __restrict__ proj,
                                                   const float* __restrict__ cw,
                                                   const float* __restrict__ cb,
                                                   unsigned short* __restrict__ xbc) {
  int ch = blockIdx.x * 256 + threadIdx.x;
  int row = blockIdx.y;
  int b = row >> 11, ll = row & 2047;
  float acc = cb[ch];
#pragma unroll
  for (int k = 0; k < 4; ++k) {
    int l2 = ll - 3 + k;
    if (l2 >= 0)
      acc += bf2f(proj[(size_t)(b * SEQ + l2) * PROJ_D + INTER_D + ch]) * cw[ch * 4 + k];
  }
  float s = acc / (1.f + __expf(-acc));
  xbc[(size_t)row * CONV_D + ch] = f2bf(s);
}

// ---------------- E1b: states = X^T @ B_decay ----------------
__global__ __launch_bounds__(256) void e1b_kernel(const unsigned short* __restrict__ xbc,
                                                  const float* __restrict__ dtg,
                                                  const float* __restrict__ acsg,
                                                  float* __restrict__ states) {
  int bid = blockIdx.x;
  int h = bid & 127, c = (bid >> 7) & 15, b = bid >> 11;
  int g = h & 7;
  int row0 = b * SEQ + c * CHK;
  __shared__ __align__(16) char smem[52736];
  unsigned short* XT = (unsigned short*)smem;
  unsigned short* BdT = (unsigned short*)(smem + 17408);
  float* Acs = (float*)(smem + 52224);
  int tid = threadIdx.x, lane = tid & 63, wv = tid >> 6;
  int fo = (lane >> 4) * 8, il = lane & 15, rl = (lane >> 4) * 4;
  if (tid < 128) Acs[tid] = acsg[(((size_t)(b * NCH + c) * NH) + h) * CHK + tid];
  __syncthreads();
#pragma unroll
  for (int j = 0; j < 4; ++j) {
    int q = tid + j * 256;
    int ll = q >> 3, p0 = (q & 7) * 8;
    int row = row0 + ll;
    float dtv = dtg[(size_t)row * NH + h];
    int4 raw = *(const int4*)(xbc + (size_t)row * CONV_D + h * PD + p0);
    unsigned short* u = (unsigned short*)&raw;
#pragma unroll
    for (int e = 0; e < 8; ++e) XT[(p0 + e) * 136 + ll] = f2bf(bf2f(u[e]) * dtv);
  }
#pragma unroll
  for (int j = 0; j < 8; ++j) {
    int q = tid + j * 256;
    int ll = q >> 4, n0 = (q & 15) * 8;
    float dec = __expf(Acs[CHK - 1] - Acs[ll]);
    int4 raw = *(const int4*)(xbc + (size_t)(row0 + ll) * CONV_D + INTER_D + g * NSD + n0);
    unsigned short* u = (unsigned short*)&raw;
#pragma unroll
    for (int e = 0; e < 8; ++e) BdT[(n0 + e) * 136 + ll] = f2bf(bf2f(u[e]) * dec);
  }
  __syncthreads();
  f32x4 st[8];
#pragma unroll
  for (int i = 0; i < 8; ++i) st[i] = (f32x4){0.f, 0.f, 0.f, 0.f};
#pragma unroll
  for (int ks = 0; ks < 4; ++ks) {
    bf16x8 a = *(const bf16x8*)&XT[(wv * 16 + il) * 136 + ks * 32 + fo];
#pragma unroll
    for (int ni = 0; ni < 8; ++ni) {
      bf16x8 bb = *(const bf16x8*)&BdT[(ni * 16 + il) * 136 + ks * 32 + fo];
      st[ni] = __builtin_amdgcn_mfma_f32_16x16x32_bf16(a, bb, st[ni], 0, 0, 0);
    }
  }
  size_t base = ((size_t)(b * NH + h) * NCH + c) * (PD * NSD);
#pragma unroll
  for (int ni = 0; ni < 8; ++ni) {
    int n = ni * 16 + il;
#pragma unroll
    for (int r = 0; r < 4; ++r) {
      int p = wv * 16 + rl + r;
      states[base + p * NSD + n] = st[ni][r];
    }
  }
}

// ---------------- E2: sequential chunk-state recurrence (4-way P-split) ----------------
__global__ __launch_bounds__(256) void e2_kernel(const float* __restrict__ acsg,
                                                 float* __restrict__ states) {
  int bid = blockIdx.x;          // (b*128+h)*4 + pg
  int bh = bid >> 2, pg = bid & 3;
  int b = bh >> 7;
  int t = threadIdx.x;
  float S[8];
#pragma unroll
  for (int j = 0; j < 8; ++j) S[j] = 0.f;
  for (int c = 0; c < NCH; ++c) {
    float alast = acsg[(((size_t)((b * NCH + c) * NH) + (bh & 127))) * CHK + (CHK - 1)];
    float dec = __expf(alast);
    size_t base = ((size_t)bh * NCH + c) * (PD * NSD) + (size_t)pg * 2048;
#pragma unroll
    for (int j = 0; j < 8; ++j) {
      size_t e = base + (size_t)j * 256 + t;
      float v = states[e];
      states[e] = S[j];
      S[j] = S[j] * dec + v;
    }
  }
}

// ---------------- E13: fused Y_diag + Y_off + D_res -> yb (single write) ----------------
__global__ __launch_bounds__(512) void e13_kernel(const unsigned short* __restrict__ xbc,
                                                  const float* __restrict__ dtg,
                                                  const float* __restrict__ acsg,
                                                  const float* __restrict__ states,
                                                  const float* __restrict__ Dp,
                                                  float* __restrict__ yb) {
  int bid = blockIdx.x;
  int h = bid & 127, c = (bid >> 7) & 15, b = bid >> 11;
  int g = h & 7;
  int row0 = b * SEQ + c * CHK;
  __shared__ __align__(16) char smem[70144];
  unsigned short* Cst = (unsigned short*)smem;            // [128][40] Gm phase
  unsigned short* Bst = (unsigned short*)(smem + 10240);  // [128][40] Gm phase
  unsigned short* Mt = (unsigned short*)smem;             // [128][136]
  unsigned short* Ct = (unsigned short*)smem;             // [128][136] (after Y_diag)
  unsigned short* XT = (unsigned short*)(smem + 34816);   // [64][136]
  unsigned short* Sp = (unsigned short*)(smem + 52224);   // [64][136]
  float* Acs = (float*)(smem + 69632);                    // [128]
  int tid = threadIdx.x, lane = tid & 63, wv = tid >> 6;  // 8 waves
  int fo = (lane >> 4) * 8, il = lane & 15, rl = (lane >> 4) * 4;
  if (tid < 128) Acs[tid] = acsg[(((size_t)(b * NCH + c) * NH) + h) * CHK + tid];

  // phase1: Gm = C @ B^T
  f32x4 gm[8];
#pragma unroll
  for (int i = 0; i < 8; ++i) gm[i] = (f32x4){0.f, 0.f, 0.f, 0.f};
  int srow = tid >> 2, scol = (tid & 3) * 8;
  for (int kc = 0; kc < 4; ++kc) {
    __syncthreads();
    *(int4*)(Cst + srow * 40 + scol) =
        *(const int4*)(xbc + (size_t)(row0 + srow) * CONV_D + INTER_D + NG * NSD + g * NSD + kc * 32 + scol);
    *(int4*)(Bst + srow * 40 + scol) =
        *(const int4*)(xbc + (size_t)(row0 + srow) * CONV_D + INTER_D + g * NSD + kc * 32 + scol);
    __syncthreads();
    bf16x8 a = *(const bf16x8*)&Cst[(wv * 16 + il) * 40 + fo];
#pragma unroll
    for (int ni = 0; ni < 8; ++ni) {
      bf16x8 bb = *(const bf16x8*)&Bst[(ni * 16 + il) * 40 + fo];
      gm[ni] = __builtin_amdgcn_mfma_f32_16x16x32_bf16(a, bb, gm[ni], 0, 0, 0);
    }
  }
  __syncthreads();
  // phase2: masked+decayed M -> Mt; stage XT = (hs*dt)^T; stage Sp = bf16(prev_states)
#pragma unroll
  for (int ni = 0; ni < 8; ++ni) {
    int s = ni * 16 + il;
#pragma unroll
    for (int r = 0; r < 4; ++r) {
      int ll = wv * 16 + rl + r;
      float v = (s <= ll) ? gm[ni][r] * __expf(Acs[ll] - Acs[s]) : 0.f;
      Mt[ll * 136 + s] = f2bf(v);
    }
  }
#pragma unroll
  for (int j = 0; j < 2; ++j) {
    int q = tid + j * 512;
    int ll = q >> 3, p0 = (q & 7) * 8;
    int row = row0 + ll;
    float dtv = dtg[(size_t)row * NH + h];
    int4 raw = *(const int4*)(xbc + (size_t)row * CONV_D + h * PD + p0);
    unsigned short* u = (unsigned short*)&raw;
#pragma unroll
    for (int e = 0; e < 8; ++e) XT[(p0 + e) * 136 + ll] = f2bf(bf2f(u[e]) * dtv);
  }
  size_t sbase = ((size_t)(b * NH + h) * NCH + c) * (PD * NSD);
#pragma unroll
  for (int j = 0; j < 2; ++j) {
    int q = tid + j * 512;
    int p = q >> 4, n0 = (q & 15) * 8;
    unsigned short tmp[8];
#pragma unroll
    for (int e = 0; e < 8; ++e) tmp[e] = f2bf(states[sbase + p * NSD + n0 + e]);
    *(int4*)(Sp + p * 136 + n0) = *(int4*)tmp;
  }
  __syncthreads();
  // phase3: Y_diag = M @ X
  f32x4 yd[4];
#pragma unroll
  for (int i = 0; i < 4; ++i) yd[i] = (f32x4){0.f, 0.f, 0.f, 0.f};
#pragma unroll
  for (int ks = 0; ks < 4; ++ks) {
    bf16x8 a = *(const bf16x8*)&Mt[(wv * 16 + il) * 136 + ks * 32 + fo];
#pragma unroll
    for (int pi = 0; pi < 4; ++pi) {
      bf16x8 bb = *(const bf16x8*)&XT[(pi * 16 + il) * 136 + ks * 32 + fo];
      yd[pi] = __builtin_amdgcn_mfma_f32_16x16x32_bf16(a, bb, yd[pi], 0, 0, 0);
    }
  }
  __syncthreads();  // all Mt reads done before Ct overwrite
  // phase4: reload full C tile into Ct (L2-hot)
#pragma unroll
  for (int j = 0; j < 4; ++j) {
    int q = tid + j * 512;
    int ll = q >> 4, n0 = (q & 15) * 8;
    *(int4*)(Ct + ll * 136 + n0) =
        *(const int4*)(xbc + (size_t)(row0 + ll) * CONV_D + INTER_D + NG * NSD + g * NSD + n0);
  }
  __syncthreads();
  // phase5: Y_off = C @ prevS^T; final write yb = Y_diag + Y_off*exp(Acs) + D*hs
  f32x4 yo[4];
#pragma unroll
  for (int i = 0; i < 4; ++i) yo[i] = (f32x4){0.f, 0.f, 0.f, 0.f};
#pragma unroll
  for (int ks = 0; ks < 4; ++ks) {
    bf16x8 a = *(const bf16x8*)&Ct[(wv * 16 + il) * 136 + ks * 32 + fo];
#pragma unroll
    for (int pi = 0; pi < 4; ++pi) {
      bf16x8 bb = *(const bf16x8*)&Sp[(pi * 16 + il) * 136 + ks * 32 + fo];
      yo[pi] = __builtin_amdgcn_mfma_f32_16x16x32_bf16(a, bb, yo[pi], 0, 0, 0);
    }
  }
  float dv = Dp[h];
#pragma unroll
  for (int pi = 0; pi < 4; ++pi) {
    int p = pi * 16 + il;
#pragma unroll
    for (int r = 0; r < 4; ++r) {
      int ll = wv * 16 + rl + r;
      int row = row0 + ll;
      float hsv = bf2f(xbc[(size_t)row * CONV_D + h * PD + p]);
      yb[(size_t)row * INTER_D + h * PD + p] =
          yd[pi][r] + yo[pi][r] * __expf(Acs[ll]) + dv * hsv;
    }
  }
}

// ---------------- F: gate silu, grouped RMSNorm -> bf16 (D_res folded into yb) ----------------
__global__ __launch_bounds__(256) void fnorm_kernel(const float* __restrict__ yb,
                                                    const unsigned short* __restrict__ proj,
                                                    const float* __restrict__ nw,
                                                    unsigned short* __restrict__ normed) {
  int row = blockIdx.x >> 3;
  int gg = blockIdx.x & 7;
  int t = threadIdx.x;
  float v[4];
  float ss = 0.f;
#pragma unroll
  for (int j = 0; j < 4; ++j) {
    int ch = gg * 1024 + j * 256 + t;
    float val = yb[(size_t)row * INTER_D + ch];
    float gt = bf2f(proj[(size_t)row * PROJ_D + ch]);
    val *= gt / (1.f + __expf(-gt));
    v[j] = val;
    ss += val * val;
  }
  __shared__ float sred[256];
  sred[t] = ss;
  __syncthreads();
  for (int ofs = 128; ofs > 0; ofs >>= 1) {
    if (t < ofs) sred[t] += sred[t + ofs];
    __syncthreads();
  }
  float rms = rsqrtf(sred[0] / 1024.f + 1e-5f);
#pragma unroll
  for (int j = 0; j < 4; ++j) {
    int ch = gg * 1024 + j * 256 + t;
    normed[(size_t)row * INTER_D + ch] = f2bf(v[j] * rms * nw[ch]);
  }
}

extern "C" void kernel_launch(void* const* d_in, const int* in_sizes, int n_in,
                              void* d_out, int out_size, void* d_ws, size_t ws_size,
                              hipStream_t stream) {
  (void)in_sizes; (void)n_in; (void)out_size; (void)ws_size;
  const float* hs = (const float*)d_in[0];
  const float* w1 = (const float*)d_in[1];
  const float* cw = (const float*)d_in[2];
  const float* cb = (const float*)d_in[3];
  const float* dtb = (const float*)d_in[4];
  const float* alog = (const float*)d_in[5];
  const float* Dp = (const float*)d_in[6];
  const float* nw = (const float*)d_in[7];
  const float* w2 = (const float*)d_in[8];
  float* out = (float*)d_out;
  char* ws = (char*)d_ws;

  unsigned short* hsb = (unsigned short*)(ws);                 // 33,554,432
  unsigned short* w1b = (unsigned short*)(ws + 33554432);      // 153,092,096 (padded to 18688 rows)
  unsigned short* w2b = (unsigned short*)(ws + 186646528);     // 67,108,864
  unsigned short* proj = (unsigned short*)(ws + 253755392);    // 152,043,520
  unsigned short* xbc = (unsigned short*)(ws + 405798912);     // 83,886,080
  float* dtg = (float*)(ws + 489684992);                       // 2,097,152
  float* acsg = (float*)(ws + 491782144);                      // 2,097,152
  float* states = (float*)(ws + 493879296);                    // 134,217,728
  float* yb = (float*)(ws + 628097024);                        // 134,217,728
  unsigned short* normed = (unsigned short*)(ws);              // reuses hsb region (dead)

  cvt_kernel<<<dim3(16384), dim3(256), 0, stream>>>(hs, hsb, (size_t)ROWS * HIDD);
  cvt_kernel<<<dim3(74240), dim3(256), 0, stream>>>(w1, w1b, (size_t)PROJ_D * HIDD);
  cvt_kernel<<<dim3(32768), dim3(256), 0, stream>>>(w2, w2b, (size_t)HIDD * INTER_D);

  gemm256<1><<<dim3(16 * 73), dim3(512), 0, stream>>>(hsb, w1b, proj, nullptr,
                                                      PROJ_D, HIDD, HIDD, 0);
  dts_kernel<<<dim3(32), dim3(128), 0, stream>>>(proj, dtb, alog, dtg, acsg);
  conv_kernel<<<dim3(40, 4096), dim3(256), 0, stream>>>(proj, cw, cb, xbc);
  e1b_kernel<<<dim3(4096), dim3(256), 0, stream>>>(xbc, dtg, acsg, states);
  e2_kernel<<<dim3(1024), dim3(256), 0, stream>>>(acsg, states);
  e13_kernel<<<dim3(4096), dim3(512), 0, stream>>>(xbc, dtg, acsg, states, Dp, yb);
  fnorm_kernel<<<dim3(32768), dim3(256), 0, stream>>>(yb, proj, nw, normed);
  gemm256<0><<<dim3(16 * 16), dim3(512), 0, stream>>>(normed, w2b, nullptr, out,
                                                      HIDD, INTER_D, INTER_D, 0);
}

// Round 10
// 1600.234 us; speedup vs baseline: 5.0416x; 5.0416x over previous
//
#include <hip/hip_runtime.h>

#define NH 128
#define PD 64
#define NSD 128
#define NG 8
#define CHK 128
#define HIDD 4096
#define INTER_D 8192
#define CONV_D 10240
#define PROJ_D 18560
#define SEQ 2048
#define ROWS 4096
#define NCH 16

typedef __attribute__((ext_vector_type(8))) short bf16x8;
typedef __attribute__((ext_vector_type(4))) float f32x4;

__device__ __forceinline__ unsigned short f2bf(float f) {
  unsigned int u = __float_as_uint(f);
  u += 0x7FFF + ((u >> 16) & 1);
  return (unsigned short)(u >> 16);
}
__device__ __forceinline__ float bf2f(unsigned short s) {
  return __uint_as_float(((unsigned int)s) << 16);
}

__device__ __forceinline__ void gld16(const unsigned short* g, unsigned short* l) {
  __builtin_amdgcn_global_load_lds(
      (__attribute__((address_space(1))) const void*)g,
      (__attribute__((address_space(3))) void*)l, 16, 0, 0);
}

#define BAR() __builtin_amdgcn_s_barrier()
#define SCHED() __builtin_amdgcn_sched_barrier(0)
#define VMCNT(n) asm volatile("s_waitcnt vmcnt(" #n ")" ::: "memory")

// BK=64 legacy swizzled read (used by non-GEMM kernels' [128][64] tiles)
__device__ __forceinline__ bf16x8 ldsfrag(const unsigned short* slot, int row, int kslot) {
  int byte = row * 128 + (((kslot ^ (row & 7)) << 4));
  return *(const bf16x8*)((const char*)slot + byte);
}

// BK=32 half-tile: 8KB, stored as [64 row-pairs][128B], XOR-swizzled.
// logical (row in 0..127, fog in 0..3): rp=row>>1, granule g=(row&1)*4+fog, slot16 s=g^(rp&7)
__device__ __forceinline__ bf16x8 ldsfrag32(const unsigned short* slot, int row, int fog) {
  int rp = row >> 1;
  int s = (((row & 1) << 2) | fog) ^ (rp & 7);
  return *(const bf16x8*)((const char*)slot + rp * 128 + (s << 4));
}

// ---------------- f32 -> bf16 convert ----------------
__global__ __launch_bounds__(256) void cvt_kernel(const float* __restrict__ in,
                                                  unsigned short* __restrict__ out,
                                                  size_t n) {
  size_t i = ((size_t)blockIdx.x * 256 + threadIdx.x) * 4;
  if (i < n) {
    float4 f = *(const float4*)(in + i);
    ushort4 o;
    o.x = f2bf(f.x); o.y = f2bf(f.y); o.z = f2bf(f.z); o.w = f2bf(f.w);
    *(ushort4*)(out + i) = o;
  }
}

// ---------------- 256^2 4-phase GEMM, BK=32, 64KB LDS ----------------
// 8 waves (2M x 4N). launch_bounds (512,2): do NOT force 4 waves/EU (R9's (512,4)
// capped VGPR at 64 -> acc spilled -> 22GB scratch traffic, 10x regression).
// With ~108 VGPR (<=128) and 64KB LDS, HW can co-schedule 2 blocks/CU on its own.
template <int OUT_BF16>
__global__ __launch_bounds__(512, 2) void gemm256(const unsigned short* __restrict__ A,
                                                  const unsigned short* __restrict__ B,
                                                  unsigned short* __restrict__ outb,
                                                  float* __restrict__ outf,
                                                  int Nreal, int Ks, int Kl, int koff) {
  __shared__ unsigned short lds[8][4096];  // 8 half-slots x 8KB = 64KB
  int tid = threadIdx.x, l = tid & 63, w = tid >> 6;
  int wm = w >> 2, wn = w & 3;
  int il = l & 15, fog = l >> 4;  // fog in 0..3
  int bid = blockIdx.x;
  int xcd = bid & 7, local = bid >> 3;
  int mt = xcd * 2 + (local & 1), nt = local >> 1;
  const unsigned short* Abase = A + (size_t)mt * 256 * Ks + koff;
  const unsigned short* Bbase = B + (size_t)nt * 256 * Ks + koff;
  int NT = Kl >> 5;

  f32x4 acc[2][2][4][2];
#pragma unroll
  for (int a = 0; a < 2; ++a)
#pragma unroll
    for (int b = 0; b < 2; ++b)
#pragma unroll
      for (int m = 0; m < 4; ++m)
#pragma unroll
        for (int n = 0; n < 2; ++n) acc[a][b][m][n] = (f32x4){0.f, 0.f, 0.f, 0.f};

  // per-lane inverse-swizzled global source for linear gld16 dest
  int gg = (l & 7) ^ ((l >> 3) & 7);
  int grow_l = ((w * 8 + (l >> 3)) << 1) | (gg >> 2);  // 0..127
  int gcol_l = (gg & 3) * 8;                           // ushort offset in 0..24

  // stage half-tile ty (0:A0 1:B0 2:A1 3:B1) of k-tile tt; ONE gld16 per thread
  auto STG = [&](int tt, int ty) {
    int tc = tt < NT ? tt : NT - 1;
    const unsigned short* g = ((ty & 1) ? Bbase : Abase) + (size_t)((ty >> 1) * 128) * Ks + tc * 32;
    unsigned short* sp = (unsigned short*)lds[(tt & 1) * 4 + ty] + w * 512;  // wave-uniform
    gld16(g + (size_t)grow_l * Ks + gcol_l, sp);
  };

#define LDA(SLOT)                                          \
  _Pragma("unroll") for (int mi = 0; mi < 4; ++mi)         \
      av[mi] = ldsfrag32(SLOT, wm * 64 + mi * 16 + il, fog);
#define LDB(QN, SLOT)                                      \
  _Pragma("unroll") for (int ni = 0; ni < 2; ++ni)         \
      bv[QN][ni] = ldsfrag32(SLOT, wn * 32 + ni * 16 + il, fog);
#define MFMA_PH(QM, QN)                                    \
  _Pragma("unroll") for (int mi = 0; mi < 4; ++mi)         \
  _Pragma("unroll") for (int ni = 0; ni < 2; ++ni)         \
      acc[QM][QN][mi][ni] = __builtin_amdgcn_mfma_f32_16x16x32_bf16( \
          av[mi], bv[QN][ni], acc[QM][QN][mi][ni], 0, 0, 0);

  // prologue: tile0 all 4 halves; leave A1 (issued last) in flight
  STG(0, 0); STG(0, 1); STG(0, 3); STG(0, 2);
  VMCNT(1);
  BAR(); SCHED();

  for (int t = 0; t < NT; ++t) {
    const unsigned short* sA0 = lds[(t & 1) * 4 + 0];
    const unsigned short* sB0 = lds[(t & 1) * 4 + 1];
    const unsigned short* sA1 = lds[(t & 1) * 4 + 2];
    const unsigned short* sB1 = lds[(t & 1) * 4 + 3];
    bf16x8 av[4], bv[2][2];
    // P1: read A0 + both B quadrants; stage A0,B0 of t+1
    LDA(sA0); LDB(0, sB0); LDB(1, sB1);
    STG(t + 1, 0); STG(t + 1, 1);
    BAR();
    __builtin_amdgcn_s_setprio(1);
    MFMA_PH(0, 0);
    __builtin_amdgcn_s_setprio(0);
    VMCNT(2);  // A1(t) landed -> safe for P3 reads
    BAR(); SCHED();
    // P2: pure MFMA; stage B1 of t+1
    STG(t + 1, 3);
    __builtin_amdgcn_s_setprio(1);
    MFMA_PH(0, 1);
    __builtin_amdgcn_s_setprio(0);
    BAR();
    // P3: read A1; stage A1 of t+1
    LDA(sA1);
    STG(t + 1, 2);
    BAR();
    __builtin_amdgcn_s_setprio(1);
    MFMA_PH(1, 0);
    __builtin_amdgcn_s_setprio(0);
    BAR();
    // P4: pure MFMA
    __builtin_amdgcn_s_setprio(1);
    MFMA_PH(1, 1);
    __builtin_amdgcn_s_setprio(0);
    VMCNT(1);  // A0,B0,B1(t+1) landed -> safe for next P1 reads
    BAR(); SCHED();
  }
  VMCNT(0);

  // epilogue: C write
  int rl = (l >> 4) * 4;
#pragma unroll
  for (int qm = 0; qm < 2; ++qm)
#pragma unroll
    for (int qn = 0; qn < 2; ++qn)
#pragma unroll
      for (int mi = 0; mi < 4; ++mi)
#pragma unroll
        for (int ni = 0; ni < 2; ++ni) {
          int grow = mt * 256 + qm * 128 + wm * 64 + mi * 16 + rl;
          int gcol = nt * 256 + qn * 128 + wn * 32 + ni * 16 + il;
          if (!OUT_BF16 || gcol < Nreal) {
#pragma unroll
            for (int r = 0; r < 4; ++r) {
              float v = acc[qm][qn][mi][ni][r];
              if (OUT_BF16)
                outb[(size_t)(grow + r) * Nreal + gcol] = f2bf(v);
              else
                outf[(size_t)(grow + r) * Nreal + gcol] = v;
            }
          }
        }
#undef LDA
#undef LDB
#undef MFMA_PH
}

// ---------------- dt softplus + A*dt cumsum ----------------
__global__ __launch_bounds__(128) void dts_kernel(const unsigned short* __restrict__ proj,
                                                  const float* __restrict__ dt_bias,
                                                  const float* __restrict__ A_log,
                                                  float* __restrict__ dtg,
                                                  float* __restrict__ acsg) {
  int bc = blockIdx.x;
  int h = threadIdx.x;
  int b = bc >> 4, c = bc & 15;
  float A = -__expf(A_log[h]);
  float bias = dt_bias[h];
  float cum = 0.f;
  int row0 = b * SEQ + c * CHK;
#pragma unroll 4
  for (int ll = 0; ll < CHK; ++ll) {
    float x = bf2f(proj[(size_t)(row0 + ll) * PROJ_D + (PROJ_D - NH) + h]) + bias;
    float d = (x > 20.f) ? x : log1pf(expf(x));
    dtg[(size_t)(row0 + ll) * NH + h] = d;
    cum += A * d;
    acsg[(((size_t)bc * NH) + h) * CHK + ll] = cum;
  }
}

// ---------------- causal depthwise conv + bias + silu ----------------
__global__ __launch_bounds__(256) void conv_kernel(const unsigned short* __restrict__ proj,
                                                   const float* __restrict__ cw,
                                                   const float* __restrict__ cb,
                                                   unsigned short* __restrict__ xbc) {
  int ch = blockIdx.x * 256 + threadIdx.x;
  int row = blockIdx.y;
  int b = row >> 11, ll = row & 2047;
  float acc = cb[ch];
#pragma unroll
  for (int k = 0; k < 4; ++k) {
    int l2 = ll - 3 + k;
    if (l2 >= 0)
      acc += bf2f(proj[(size_t)(b * SEQ + l2) * PROJ_D + INTER_D + ch]) * cw[ch * 4 + k];
  }
  float s = acc / (1.f + __expf(-acc));
  xbc[(size_t)row * CONV_D + ch] = f2bf(s);
}

// ---------------- E1b: states = X^T @ B_decay ----------------
__global__ __launch_bounds__(256) void e1b_kernel(const unsigned short* __restrict__ xbc,
                                                  const float* __restrict__ dtg,
                                                  const float* __restrict__ acsg,
                                                  float* __restrict__ states) {
  int bid = blockIdx.x;
  int h = bid & 127, c = (bid >> 7) & 15, b = bid >> 11;
  int g = h & 7;
  int row0 = b * SEQ + c * CHK;
  __shared__ __align__(16) char smem[52736];
  unsigned short* XT = (unsigned short*)smem;
  unsigned short* BdT = (unsigned short*)(smem + 17408);
  float* Acs = (float*)(smem + 52224);
  int tid = threadIdx.x, lane = tid & 63, wv = tid >> 6;
  int fo = (lane >> 4) * 8, il = lane & 15, rl = (lane >> 4) * 4;
  if (tid < 128) Acs[tid] = acsg[(((size_t)(b * NCH + c) * NH) + h) * CHK + tid];
  __syncthreads();
#pragma unroll
  for (int j = 0; j < 4; ++j) {
    int q = tid + j * 256;
    int ll = q >> 3, p0 = (q & 7) * 8;
    int row = row0 + ll;
    float dtv = dtg[(size_t)row * NH + h];
    int4 raw = *(const int4*)(xbc + (size_t)row * CONV_D + h * PD + p0);
    unsigned short* u = (unsigned short*)&raw;
#pragma unroll
    for (int e = 0; e < 8; ++e) XT[(p0 + e) * 136 + ll] = f2bf(bf2f(u[e]) * dtv);
  }
#pragma unroll
  for (int j = 0; j < 8; ++j) {
    int q = tid + j * 256;
    int ll = q >> 4, n0 = (q & 15) * 8;
    float dec = __expf(Acs[CHK - 1] - Acs[ll]);
    int4 raw = *(const int4*)(xbc + (size_t)(row0 + ll) * CONV_D + INTER_D + g * NSD + n0);
    unsigned short* u = (unsigned short*)&raw;
#pragma unroll
    for (int e = 0; e < 8; ++e) BdT[(n0 + e) * 136 + ll] = f2bf(bf2f(u[e]) * dec);
  }
  __syncthreads();
  f32x4 st[8];
#pragma unroll
  for (int i = 0; i < 8; ++i) st[i] = (f32x4){0.f, 0.f, 0.f, 0.f};
#pragma unroll
  for (int ks = 0; ks < 4; ++ks) {
    bf16x8 a = *(const bf16x8*)&XT[(wv * 16 + il) * 136 + ks * 32 + fo];
#pragma unroll
    for (int ni = 0; ni < 8; ++ni) {
      bf16x8 bb = *(const bf16x8*)&BdT[(ni * 16 + il) * 136 + ks * 32 + fo];
      st[ni] = __builtin_amdgcn_mfma_f32_16x16x32_bf16(a, bb, st[ni], 0, 0, 0);
    }
  }
  size_t base = ((size_t)(b * NH + h) * NCH + c) * (PD * NSD);
#pragma unroll
  for (int ni = 0; ni < 8; ++ni) {
    int n = ni * 16 + il;
#pragma unroll
    for (int r = 0; r < 4; ++r) {
      int p = wv * 16 + rl + r;
      states[base + p * NSD + n] = st[ni][r];
    }
  }
}

// ---------------- E2: sequential chunk-state recurrence (4-way P-split) ----------------
__global__ __launch_bounds__(256) void e2_kernel(const float* __restrict__ acsg,
                                                 float* __restrict__ states) {
  int bid = blockIdx.x;          // (b*128+h)*4 + pg
  int bh = bid >> 2, pg = bid & 3;
  int b = bh >> 7;
  int t = threadIdx.x;
  float S[8];
#pragma unroll
  for (int j = 0; j < 8; ++j) S[j] = 0.f;
  for (int c = 0; c < NCH; ++c) {
    float alast = acsg[(((size_t)((b * NCH + c) * NH) + (bh & 127))) * CHK + (CHK - 1)];
    float dec = __expf(alast);
    size_t base = ((size_t)bh * NCH + c) * (PD * NSD) + (size_t)pg * 2048;
#pragma unroll
    for (int j = 0; j < 8; ++j) {
      size_t e = base + (size_t)j * 256 + t;
      float v = states[e];
      states[e] = S[j];
      S[j] = S[j] * dec + v;
    }
  }
}

// ---------------- E13: fused Y_diag + Y_off + D_res -> yb (single write) ----------------
__global__ __launch_bounds__(512) void e13_kernel(const unsigned short* __restrict__ xbc,
                                                  const float* __restrict__ dtg,
                                                  const float* __restrict__ acsg,
                                                  const float* __restrict__ states,
                                                  const float* __restrict__ Dp,
                                                  float* __restrict__ yb) {
  int bid = blockIdx.x;
  int h = bid & 127, c = (bid >> 7) & 15, b = bid >> 11;
  int g = h & 7;
  int row0 = b * SEQ + c * CHK;
  __shared__ __align__(16) char smem[70144];
  unsigned short* Cst = (unsigned short*)smem;            // [128][40] Gm phase
  unsigned short* Bst = (unsigned short*)(smem + 10240);  // [128][40] Gm phase
  unsigned short* Mt = (unsigned short*)smem;             // [128][136]
  unsigned short* Ct = (unsigned short*)smem;             // [128][136] (after Y_diag)
  unsigned short* XT = (unsigned short*)(smem + 34816);   // [64][136]
  unsigned short* Sp = (unsigned short*)(smem + 52224);   // [64][136]
  float* Acs = (float*)(smem + 69632);                    // [128]
  int tid = threadIdx.x, lane = tid & 63, wv = tid >> 6;  // 8 waves
  int fo = (lane >> 4) * 8, il = lane & 15, rl = (lane >> 4) * 4;
  if (tid < 128) Acs[tid] = acsg[(((size_t)(b * NCH + c) * NH) + h) * CHK + tid];

  // phase1: Gm = C @ B^T
  f32x4 gm[8];
#pragma unroll
  for (int i = 0; i < 8; ++i) gm[i] = (f32x4){0.f, 0.f, 0.f, 0.f};
  int srow = tid >> 2, scol = (tid & 3) * 8;
  for (int kc = 0; kc < 4; ++kc) {
    __syncthreads();
    *(int4*)(Cst + srow * 40 + scol) =
        *(const int4*)(xbc + (size_t)(row0 + srow) * CONV_D + INTER_D + NG * NSD + g * NSD + kc * 32 + scol);
    *(int4*)(Bst + srow * 40 + scol) =
        *(const int4*)(xbc + (size_t)(row0 + srow) * CONV_D + INTER_D + g * NSD + kc * 32 + scol);
    __syncthreads();
    bf16x8 a = *(const bf16x8*)&Cst[(wv * 16 + il) * 40 + fo];
#pragma unroll
    for (int ni = 0; ni < 8; ++ni) {
      bf16x8 bb = *(const bf16x8*)&Bst[(ni * 16 + il) * 40 + fo];
      gm[ni] = __builtin_amdgcn_mfma_f32_16x16x32_bf16(a, bb, gm[ni], 0, 0, 0);
    }
  }
  __syncthreads();
  // phase2: masked+decayed M -> Mt; stage XT = (hs*dt)^T; stage Sp = bf16(prev_states)
#pragma unroll
  for (int ni = 0; ni < 8; ++ni) {
    int s = ni * 16 + il;
#pragma unroll
    for (int r = 0; r < 4; ++r) {
      int ll = wv * 16 + rl + r;
      float v = (s <= ll) ? gm[ni][r] * __expf(Acs[ll] - Acs[s]) : 0.f;
      Mt[ll * 136 + s] = f2bf(v);
    }
  }
#pragma unroll
  for (int j = 0; j < 2; ++j) {
    int q = tid + j * 512;
    int ll = q >> 3, p0 = (q & 7) * 8;
    int row = row0 + ll;
    float dtv = dtg[(size_t)row * NH + h];
    int4 raw = *(const int4*)(xbc + (size_t)row * CONV_D + h * PD + p0);
    unsigned short* u = (unsigned short*)&raw;
#pragma unroll
    for (int e = 0; e < 8; ++e) XT[(p0 + e) * 136 + ll] = f2bf(bf2f(u[e]) * dtv);
  }
  size_t sbase = ((size_t)(b * NH + h) * NCH + c) * (PD * NSD);
#pragma unroll
  for (int j = 0; j < 2; ++j) {
    int q = tid + j * 512;
    int p = q >> 4, n0 = (q & 15) * 8;
    unsigned short tmp[8];
#pragma unroll
    for (int e = 0; e < 8; ++e) tmp[e] = f2bf(states[sbase + p * NSD + n0 + e]);
    *(int4*)(Sp + p * 136 + n0) = *(int4*)tmp;
  }
  __syncthreads();
  // phase3: Y_diag = M @ X
  f32x4 yd[4];
#pragma unroll
  for (int i = 0; i < 4; ++i) yd[i] = (f32x4){0.f, 0.f, 0.f, 0.f};
#pragma unroll
  for (int ks = 0; ks < 4; ++ks) {
    bf16x8 a = *(const bf16x8*)&Mt[(wv * 16 + il) * 136 + ks * 32 + fo];
#pragma unroll
    for (int pi = 0; pi < 4; ++pi) {
      bf16x8 bb = *(const bf16x8*)&XT[(pi * 16 + il) * 136 + ks * 32 + fo];
      yd[pi] = __builtin_amdgcn_mfma_f32_16x16x32_bf16(a, bb, yd[pi], 0, 0, 0);
    }
  }
  __syncthreads();  // all Mt reads done before Ct overwrite
  // phase4: reload full C tile into Ct (L2-hot)
#pragma unroll
  for (int j = 0; j < 4; ++j) {
    int q = tid + j * 512;
    int ll = q >> 4, n0 = (q & 15) * 8;
    *(int4*)(Ct + ll * 136 + n0) =
        *(const int4*)(xbc + (size_t)(row0 + ll) * CONV_D + INTER_D + NG * NSD + g * NSD + n0);
  }
  __syncthreads();
  // phase5: Y_off = C @ prevS^T; final write yb = Y_diag + Y_off*exp(Acs) + D*hs
  f32x4 yo[4];
#pragma unroll
  for (int i = 0; i < 4; ++i) yo[i] = (f32x4){0.f, 0.f, 0.f, 0.f};
#pragma unroll
  for (int ks = 0; ks < 4; ++ks) {
    bf16x8 a = *(const bf16x8*)&Ct[(wv * 16 + il) * 136 + ks * 32 + fo];
#pragma unroll
    for (int pi = 0; pi < 4; ++pi) {
      bf16x8 bb = *(const bf16x8*)&Sp[(pi * 16 + il) * 136 + ks * 32 + fo];
      yo[pi] = __builtin_amdgcn_mfma_f32_16x16x32_bf16(a, bb, yo[pi], 0, 0, 0);
    }
  }
  float dv = Dp[h];
#pragma unroll
  for (int pi = 0; pi < 4; ++pi) {
    int p = pi * 16 + il;
#pragma unroll
    for (int r = 0; r < 4; ++r) {
      int ll = wv * 16 + rl + r;
      int row = row0 + ll;
      float hsv = bf2f(xbc[(size_t)row * CONV_D + h * PD + p]);
      yb[(size_t)row * INTER_D + h * PD + p] =
          yd[pi][r] + yo[pi][r] * __expf(Acs[ll]) + dv * hsv;
    }
  }
}

// ---------------- F: gate silu, grouped RMSNorm -> bf16 (D_res folded into yb) ----------------
__global__ __launch_bounds__(256) void fnorm_kernel(const float* __restrict__ yb,
                                                    const unsigned short* __restrict__ proj,
                                                    const float* __restrict__ nw,
                                                    unsigned short* __restrict__ normed) {
  int row = blockIdx.x >> 3;
  int gg = blockIdx.x & 7;
  int t = threadIdx.x;
  float v[4];
  float ss = 0.f;
#pragma unroll
  for (int j = 0; j < 4; ++j) {
    int ch = gg * 1024 + j * 256 + t;
    float val = yb[(size_t)row * INTER_D + ch];
    float gt = bf2f(proj[(size_t)row * PROJ_D + ch]);
    val *= gt / (1.f + __expf(-gt));
    v[j] = val;
    ss += val * val;
  }
  __shared__ float sred[256];
  sred[t] = ss;
  __syncthreads();
  for (int ofs = 128; ofs > 0; ofs >>= 1) {
    if (t < ofs) sred[t] += sred[t + ofs];
    __syncthreads();
  }
  float rms = rsqrtf(sred[0] / 1024.f + 1e-5f);
#pragma unroll
  for (int j = 0; j < 4; ++j) {
    int ch = gg * 1024 + j * 256 + t;
    normed[(size_t)row * INTER_D + ch] = f2bf(v[j] * rms * nw[ch]);
  }
}

extern "C" void kernel_launch(void* const* d_in, const int* in_sizes, int n_in,
                              void* d_out, int out_size, void* d_ws, size_t ws_size,
                              hipStream_t stream) {
  (void)in_sizes; (void)n_in; (void)out_size; (void)ws_size;
  const float* hs = (const float*)d_in[0];
  const float* w1 = (const float*)d_in[1];
  const float* cw = (const float*)d_in[2];
  const float* cb = (const float*)d_in[3];
  const float* dtb = (const float*)d_in[4];
  const float* alog = (const float*)d_in[5];
  const float* Dp = (const float*)d_in[6];
  const float* nw = (const float*)d_in[7];
  const float* w2 = (const float*)d_in[8];
  float* out = (float*)d_out;
  char* ws = (char*)d_ws;

  unsigned short* hsb = (unsigned short*)(ws);                 // 33,554,432
  unsigned short* w1b = (unsigned short*)(ws + 33554432);      // 153,092,096 (padded to 18688 rows)
  unsigned short* w2b = (unsigned short*)(ws + 186646528);     // 67,108,864
  unsigned short* proj = (unsigned short*)(ws + 253755392);    // 152,043,520
  unsigned short* xbc = (unsigned short*)(ws + 405798912);     // 83,886,080
  float* dtg = (float*)(ws + 489684992);                       // 2,097,152
  float* acsg = (float*)(ws + 491782144);                      // 2,097,152
  float* states = (float*)(ws + 493879296);                    // 134,217,728
  float* yb = (float*)(ws + 628097024);                        // 134,217,728
  unsigned short* normed = (unsigned short*)(ws);              // reuses hsb region (dead)

  cvt_kernel<<<dim3(16384), dim3(256), 0, stream>>>(hs, hsb, (size_t)ROWS * HIDD);
  cvt_kernel<<<dim3(74240), dim3(256), 0, stream>>>(w1, w1b, (size_t)PROJ_D * HIDD);
  cvt_kernel<<<dim3(32768), dim3(256), 0, stream>>>(w2, w2b, (size_t)HIDD * INTER_D);

  gemm256<1><<<dim3(16 * 73), dim3(512), 0, stream>>>(hsb, w1b, proj, nullptr,
                                                      PROJ_D, HIDD, HIDD, 0);
  dts_kernel<<<dim3(32), dim3(128), 0, stream>>>(proj, dtb, alog, dtg, acsg);
  conv_kernel<<<dim3(40, 4096), dim3(256), 0, stream>>>(proj, cw, cb, xbc);
  e1b_kernel<<<dim3(4096), dim3(256), 0, stream>>>(xbc, dtg, acsg, states);
  e2_kernel<<<dim3(1024), dim3(256), 0, stream>>>(acsg, states);
  e13_kernel<<<dim3(4096), dim3(512), 0, stream>>>(xbc, dtg, acsg, states, Dp, yb);
  fnorm_kernel<<<dim3(32768), dim3(256), 0, stream>>>(yb, proj, nw, normed);
  gemm256<0><<<dim3(16 * 16), dim3(512), 0, stream>>>(normed, w2b, nullptr, out,
                                                      HIDD, INTER_D, INTER_D, 0);
}

// Round 11
// 1436.005 us; speedup vs baseline: 5.6182x; 1.1144x over previous
//
#include <hip/hip_runtime.h>

#define NH 128
#define PD 64
#define NSD 128
#define NG 8
#define CHK 128
#define HIDD 4096
#define INTER_D 8192
#define CONV_D 10240
#define PROJ_D 18560
#define SEQ 2048
#define ROWS 4096
#define NCH 16

typedef __attribute__((ext_vector_type(8))) short bf16x8;
typedef __attribute__((ext_vector_type(4))) float f32x4;

__device__ __forceinline__ unsigned short f2bf(float f) {
  unsigned int u = __float_as_uint(f);
  u += 0x7FFF + ((u >> 16) & 1);
  return (unsigned short)(u >> 16);
}
__device__ __forceinline__ float bf2f(unsigned short s) {
  return __uint_as_float(((unsigned int)s) << 16);
}

__device__ __forceinline__ void gld16(const unsigned short* g, unsigned short* l) {
  __builtin_amdgcn_global_load_lds(
      (__attribute__((address_space(1))) const void*)g,
      (__attribute__((address_space(3))) void*)l, 16, 0, 0);
}

#define BAR() __builtin_amdgcn_s_barrier()
#define SCHED() __builtin_amdgcn_sched_barrier(0)
#define VMCNT(n) asm volatile("s_waitcnt vmcnt(" #n ")" ::: "memory")

// swizzled LDS fragment read: slot is a [128][64] bf16 half-tile (16KB)
__device__ __forceinline__ bf16x8 ldsfrag(const unsigned short* slot, int row, int kslot) {
  int byte = row * 128 + (((kslot ^ (row & 7)) << 4));
  return *(const bf16x8*)((const char*)slot + byte);
}

// ---------------- f32 -> bf16 convert ----------------
__global__ __launch_bounds__(256) void cvt_kernel(const float* __restrict__ in,
                                                  unsigned short* __restrict__ out,
                                                  size_t n) {
  size_t i = ((size_t)blockIdx.x * 256 + threadIdx.x) * 4;
  if (i < n) {
    float4 f = *(const float4*)(in + i);
    ushort4 o;
    o.x = f2bf(f.x); o.y = f2bf(f.y); o.z = f2bf(f.z); o.w = f2bf(f.w);
    *(ushort4*)(out + i) = o;
  }
}

// ---------------- 256^2 4-phase GEMM, BK=64 (PROVEN; do not edit) ----------------
// 8 waves (2M x 4N). Stage always into the opposite buffer (race-free).
// 608-612us on GEMM1, reproduced rounds 3/5/7/8. All schedule variants regressed:
// burst(R4), t+2-prefetch(R6, raced), split-K(R8), BK=32(R9/R10).
template <int OUT_BF16>
__global__ __launch_bounds__(512, 2) void gemm256(const unsigned short* __restrict__ A,
                                                  const unsigned short* __restrict__ B,
                                                  unsigned short* __restrict__ outb,
                                                  float* __restrict__ outf,
                                                  int Nreal, int Ks, int Kl, int koff) {
  __shared__ unsigned short lds[8][8192];  // 8 half-slots x 16KB = 128KB
  int tid = threadIdx.x, l = tid & 63, w = tid >> 6;
  int wm = w >> 2, wn = w & 3;
  int il = l & 15, fog = l >> 4;
  int bid = blockIdx.x;
  int xcd = bid & 7, local = bid >> 3;
  int mt = xcd * 2 + (local & 1), nt = local >> 1;
  const unsigned short* Abase = A + (size_t)mt * 256 * Ks + koff;
  const unsigned short* Bbase = B + (size_t)nt * 256 * Ks + koff;
  int NT = Kl >> 6;

  f32x4 acc[2][2][4][2];
#pragma unroll
  for (int a = 0; a < 2; ++a)
#pragma unroll
    for (int b = 0; b < 2; ++b)
#pragma unroll
      for (int m = 0; m < 4; ++m)
#pragma unroll
        for (int n = 0; n < 2; ++n) acc[a][b][m][n] = (f32x4){0.f, 0.f, 0.f, 0.f};

  auto STG = [&](int tt, int ty) {
    int tc = tt < NT ? tt : NT - 1;
    const unsigned short* g = ((ty & 1) ? Bbase : Abase) + (size_t)((ty >> 1) * 128) * Ks + tc * 64;
    unsigned short* sp = (unsigned short*)lds[(tt & 1) * 4 + ty];
#pragma unroll
    for (int j = 0; j < 2; ++j) {
      int row = (j * 8 + w) * 8 + (l >> 3);
      int scol = ((l & 7) ^ (row & 7)) * 8;  // inverse-swizzled global source
      gld16(g + (size_t)row * Ks + scol, sp + (j * 8 + w) * 512);
    }
  };

#define LDA(SLOT)                                          \
  _Pragma("unroll") for (int mi = 0; mi < 4; ++mi)         \
  _Pragma("unroll") for (int kk = 0; kk < 2; ++kk)         \
      av[mi][kk] = ldsfrag(SLOT, wm * 64 + mi * 16 + il, kk * 4 + fog);
#define LDB(QN, SLOT)                                      \
  _Pragma("unroll") for (int ni = 0; ni < 2; ++ni)         \
  _Pragma("unroll") for (int kk = 0; kk < 2; ++kk)         \
      bv[QN][ni][kk] = ldsfrag(SLOT, wn * 32 + ni * 16 + il, kk * 4 + fog);
#define MFMA_PH(QM, QN)                                    \
  _Pragma("unroll") for (int mi = 0; mi < 4; ++mi)         \
  _Pragma("unroll") for (int ni = 0; ni < 2; ++ni)         \
  _Pragma("unroll") for (int kk = 0; kk < 2; ++kk)         \
      acc[QM][QN][mi][ni] = __builtin_amdgcn_mfma_f32_16x16x32_bf16( \
          av[mi][kk], bv[QN][ni][kk], acc[QM][QN][mi][ni], 0, 0, 0);

  // prologue: tile0 all 4 halves; leave A1 (ty2) in flight
  STG(0, 0); STG(0, 1); STG(0, 3); STG(0, 2);
  VMCNT(2);
  BAR(); SCHED();

  for (int t = 0; t < NT; ++t) {
    const unsigned short* sA0 = lds[(t & 1) * 4 + 0];
    const unsigned short* sB0 = lds[(t & 1) * 4 + 1];
    const unsigned short* sA1 = lds[(t & 1) * 4 + 2];
    const unsigned short* sB1 = lds[(t & 1) * 4 + 3];
    bf16x8 av[4][2], bv[2][2][2];
    // P1: read A0 + both B quadrants; stage A0,B0 of t+1
    LDA(sA0); LDB(0, sB0); LDB(1, sB1);
    STG(t + 1, 0); STG(t + 1, 1);
    BAR();
    __builtin_amdgcn_s_setprio(1);
    MFMA_PH(0, 0);
    __builtin_amdgcn_s_setprio(0);
    VMCNT(4);  // A1(t) landed (staged prev iter) -> safe for P3 reads
    BAR(); SCHED();
    // P2: pure MFMA; stage B1 of t+1
    STG(t + 1, 3);
    __builtin_amdgcn_s_setprio(1);
    MFMA_PH(0, 1);
    __builtin_amdgcn_s_setprio(0);
    BAR();
    // P3: read A1; stage A1 of t+1
    LDA(sA1);
    STG(t + 1, 2);
    BAR();
    __builtin_amdgcn_s_setprio(1);
    MFMA_PH(1, 0);
    __builtin_amdgcn_s_setprio(0);
    BAR();
    // P4: pure MFMA
    __builtin_amdgcn_s_setprio(1);
    MFMA_PH(1, 1);
    __builtin_amdgcn_s_setprio(0);
    VMCNT(2);  // A0,B0,B1(t+1) landed -> safe for next P1 reads
    BAR(); SCHED();
  }
  VMCNT(0);

  // epilogue: C write
  int rl = (l >> 4) * 4;
#pragma unroll
  for (int qm = 0; qm < 2; ++qm)
#pragma unroll
    for (int qn = 0; qn < 2; ++qn)
#pragma unroll
      for (int mi = 0; mi < 4; ++mi)
#pragma unroll
        for (int ni = 0; ni < 2; ++ni) {
          int grow = mt * 256 + qm * 128 + wm * 64 + mi * 16 + rl;
          int gcol = nt * 256 + qn * 128 + wn * 32 + ni * 16 + il;
          if (!OUT_BF16 || gcol < Nreal) {
#pragma unroll
            for (int r = 0; r < 4; ++r) {
              float v = acc[qm][qn][mi][ni][r];
              if (OUT_BF16)
                outb[(size_t)(grow + r) * Nreal + gcol] = f2bf(v);
              else
                outf[(size_t)(grow + r) * Nreal + gcol] = v;
            }
          }
        }
#undef LDA
#undef LDB
#undef MFMA_PH
}

// ---------------- dt softplus + A*dt cumsum ----------------
__global__ __launch_bounds__(128) void dts_kernel(const unsigned short* __restrict__ proj,
                                                  const float* __restrict__ dt_bias,
                                                  const float* __restrict__ A_log,
                                                  float* __restrict__ dtg,
                                                  float* __restrict__ acsg) {
  int bc = blockIdx.x;
  int h = threadIdx.x;
  int b = bc >> 4, c = bc & 15;
  float A = -__expf(A_log[h]);
  float bias = dt_bias[h];
  float cum = 0.f;
  int row0 = b * SEQ + c * CHK;
#pragma unroll 4
  for (int ll = 0; ll < CHK; ++ll) {
    float x = bf2f(proj[(size_t)(row0 + ll) * PROJ_D + (PROJ_D - NH) + h]) + bias;
    float d = (x > 20.f) ? x : log1pf(expf(x));
    dtg[(size_t)(row0 + ll) * NH + h] = d;
    cum += A * d;
    acsg[(((size_t)bc * NH) + h) * CHK + ll] = cum;
  }
}

// ---------------- causal depthwise conv + bias + silu ----------------
__global__ __launch_bounds__(256) void conv_kernel(const unsigned short* __restrict__ proj,
                                                   const float* __restrict__ cw,
                                                   const float* __restrict__ cb,
                                                   unsigned short* __restrict__ xbc) {
  int ch = blockIdx.x * 256 + threadIdx.x;
  int row = blockIdx.y;
  int b = row >> 11, ll = row & 2047;
  float acc = cb[ch];
#pragma unroll
  for (int k = 0; k < 4; ++k) {
    int l2 = ll - 3 + k;
    if (l2 >= 0)
      acc += bf2f(proj[(size_t)(b * SEQ + l2) * PROJ_D + INTER_D + ch]) * cw[ch * 4 + k];
  }
  float s = acc / (1.f + __expf(-acc));
  xbc[(size_t)row * CONV_D + ch] = f2bf(s);
}

// ---------------- E1b: states = X^T @ B_decay (f32 out) ----------------
__global__ __launch_bounds__(256) void e1b_kernel(const unsigned short* __restrict__ xbc,
                                                  const float* __restrict__ dtg,
                                                  const float* __restrict__ acsg,
                                                  float* __restrict__ states) {
  int bid = blockIdx.x;
  int h = bid & 127, c = (bid >> 7) & 15, b = bid >> 11;
  int g = h & 7;
  int row0 = b * SEQ + c * CHK;
  __shared__ __align__(16) char smem[52736];
  unsigned short* XT = (unsigned short*)smem;
  unsigned short* BdT = (unsigned short*)(smem + 17408);
  float* Acs = (float*)(smem + 52224);
  int tid = threadIdx.x, lane = tid & 63, wv = tid >> 6;
  int fo = (lane >> 4) * 8, il = lane & 15, rl = (lane >> 4) * 4;
  if (tid < 128) Acs[tid] = acsg[(((size_t)(b * NCH + c) * NH) + h) * CHK + tid];
  __syncthreads();
#pragma unroll
  for (int j = 0; j < 4; ++j) {
    int q = tid + j * 256;
    int ll = q >> 3, p0 = (q & 7) * 8;
    int row = row0 + ll;
    float dtv = dtg[(size_t)row * NH + h];
    int4 raw = *(const int4*)(xbc + (size_t)row * CONV_D + h * PD + p0);
    unsigned short* u = (unsigned short*)&raw;
#pragma unroll
    for (int e = 0; e < 8; ++e) XT[(p0 + e) * 136 + ll] = f2bf(bf2f(u[e]) * dtv);
  }
#pragma unroll
  for (int j = 0; j < 8; ++j) {
    int q = tid + j * 256;
    int ll = q >> 4, n0 = (q & 15) * 8;
    float dec = __expf(Acs[CHK - 1] - Acs[ll]);
    int4 raw = *(const int4*)(xbc + (size_t)(row0 + ll) * CONV_D + INTER_D + g * NSD + n0);
    unsigned short* u = (unsigned short*)&raw;
#pragma unroll
    for (int e = 0; e < 8; ++e) BdT[(n0 + e) * 136 + ll] = f2bf(bf2f(u[e]) * dec);
  }
  __syncthreads();
  f32x4 st[8];
#pragma unroll
  for (int i = 0; i < 8; ++i) st[i] = (f32x4){0.f, 0.f, 0.f, 0.f};
#pragma unroll
  for (int ks = 0; ks < 4; ++ks) {
    bf16x8 a = *(const bf16x8*)&XT[(wv * 16 + il) * 136 + ks * 32 + fo];
#pragma unroll
    for (int ni = 0; ni < 8; ++ni) {
      bf16x8 bb = *(const bf16x8*)&BdT[(ni * 16 + il) * 136 + ks * 32 + fo];
      st[ni] = __builtin_amdgcn_mfma_f32_16x16x32_bf16(a, bb, st[ni], 0, 0, 0);
    }
  }
  size_t base = ((size_t)(b * NH + h) * NCH + c) * (PD * NSD);
#pragma unroll
  for (int ni = 0; ni < 8; ++ni) {
    int n = ni * 16 + il;
#pragma unroll
    for (int r = 0; r < 4; ++r) {
      int p = wv * 16 + rl + r;
      states[base + p * NSD + n] = st[ni][r];
    }
  }
}

// ---------------- E2: chunk-state scan; emits prev_states as bf16 ----------------
// Reads f32 states (written once by e1b); accumulates in f32 regs; writes bf16 prevs.
// Rounding point identical to old e13 (which rounded f32 states to bf16) -> no accuracy change.
__global__ __launch_bounds__(256) void e2_kernel(const float* __restrict__ acsg,
                                                 const float* __restrict__ states,
                                                 unsigned short* __restrict__ prevs) {
  int bid = blockIdx.x;          // (b*128+h)*4 + pg
  int bh = bid >> 2, pg = bid & 3;
  int b = bh >> 7;
  int t = threadIdx.x;
  float S[8];
#pragma unroll
  for (int j = 0; j < 8; ++j) S[j] = 0.f;
  for (int c = 0; c < NCH; ++c) {
    float alast = acsg[(((size_t)((b * NCH + c) * NH) + (bh & 127))) * CHK + (CHK - 1)];
    float dec = __expf(alast);
    size_t base = ((size_t)bh * NCH + c) * (PD * NSD) + (size_t)pg * 2048;
#pragma unroll
    for (int j = 0; j < 8; ++j) {
      size_t e = base + (size_t)j * 256 + t;
      float v = states[e];
      prevs[e] = f2bf(S[j]);
      S[j] = S[j] * dec + v;
    }
  }
}

// ---------------- E13: fused Y_diag + Y_off + D_res -> yb (bf16 out) ----------------
__global__ __launch_bounds__(512) void e13_kernel(const unsigned short* __restrict__ xbc,
                                                  const float* __restrict__ dtg,
                                                  const float* __restrict__ acsg,
                                                  const unsigned short* __restrict__ prevs,
                                                  const float* __restrict__ Dp,
                                                  unsigned short* __restrict__ ybh) {
  int bid = blockIdx.x;
  int h = bid & 127, c = (bid >> 7) & 15, b = bid >> 11;
  int g = h & 7;
  int row0 = b * SEQ + c * CHK;
  __shared__ __align__(16) char smem[70144];
  unsigned short* Cst = (unsigned short*)smem;            // [128][40] Gm phase
  unsigned short* Bst = (unsigned short*)(smem + 10240);  // [128][40] Gm phase
  unsigned short* Mt = (unsigned short*)smem;             // [128][136]
  unsigned short* Ct = (unsigned short*)smem;             // [128][136] (after Y_diag)
  unsigned short* XT = (unsigned short*)(smem + 34816);   // [64][136]
  unsigned short* Sp = (unsigned short*)(smem + 52224);   // [64][136]
  float* Acs = (float*)(smem + 69632);                    // [128]
  int tid = threadIdx.x, lane = tid & 63, wv = tid >> 6;  // 8 waves
  int fo = (lane >> 4) * 8, il = lane & 15, rl = (lane >> 4) * 4;
  if (tid < 128) Acs[tid] = acsg[(((size_t)(b * NCH + c) * NH) + h) * CHK + tid];

  // phase1: Gm = C @ B^T
  f32x4 gm[8];
#pragma unroll
  for (int i = 0; i < 8; ++i) gm[i] = (f32x4){0.f, 0.f, 0.f, 0.f};
  int srow = tid >> 2, scol = (tid & 3) * 8;
  for (int kc = 0; kc < 4; ++kc) {
    __syncthreads();
    *(int4*)(Cst + srow * 40 + scol) =
        *(const int4*)(xbc + (size_t)(row0 + srow) * CONV_D + INTER_D + NG * NSD + g * NSD + kc * 32 + scol);
    *(int4*)(Bst + srow * 40 + scol) =
        *(const int4*)(xbc + (size_t)(row0 + srow) * CONV_D + INTER_D + g * NSD + kc * 32 + scol);
    __syncthreads();
    bf16x8 a = *(const bf16x8*)&Cst[(wv * 16 + il) * 40 + fo];
#pragma unroll
    for (int ni = 0; ni < 8; ++ni) {
      bf16x8 bb = *(const bf16x8*)&Bst[(ni * 16 + il) * 40 + fo];
      gm[ni] = __builtin_amdgcn_mfma_f32_16x16x32_bf16(a, bb, gm[ni], 0, 0, 0);
    }
  }
  __syncthreads();
  // phase2: masked+decayed M -> Mt; stage XT = (hs*dt)^T; stage Sp = prevs (bf16 copy)
#pragma unroll
  for (int ni = 0; ni < 8; ++ni) {
    int s = ni * 16 + il;
#pragma unroll
    for (int r = 0; r < 4; ++r) {
      int ll = wv * 16 + rl + r;
      float v = (s <= ll) ? gm[ni][r] * __expf(Acs[ll] - Acs[s]) : 0.f;
      Mt[ll * 136 + s] = f2bf(v);
    }
  }
#pragma unroll
  for (int j = 0; j < 2; ++j) {
    int q = tid + j * 512;
    int ll = q >> 3, p0 = (q & 7) * 8;
    int row = row0 + ll;
    float dtv = dtg[(size_t)row * NH + h];
    int4 raw = *(const int4*)(xbc + (size_t)row * CONV_D + h * PD + p0);
    unsigned short* u = (unsigned short*)&raw;
#pragma unroll
    for (int e = 0; e < 8; ++e) XT[(p0 + e) * 136 + ll] = f2bf(bf2f(u[e]) * dtv);
  }
  size_t sbase = ((size_t)(b * NH + h) * NCH + c) * (PD * NSD);
#pragma unroll
  for (int j = 0; j < 2; ++j) {
    int q = tid + j * 512;
    int p = q >> 4, n0 = (q & 15) * 8;
    *(int4*)(Sp + p * 136 + n0) = *(const int4*)(prevs + sbase + p * NSD + n0);
  }
  __syncthreads();
  // phase3: Y_diag = M @ X
  f32x4 yd[4];
#pragma unroll
  for (int i = 0; i < 4; ++i) yd[i] = (f32x4){0.f, 0.f, 0.f, 0.f};
#pragma unroll
  for (int ks = 0; ks < 4; ++ks) {
    bf16x8 a = *(const bf16x8*)&Mt[(wv * 16 + il) * 136 + ks * 32 + fo];
#pragma unroll
    for (int pi = 0; pi < 4; ++pi) {
      bf16x8 bb = *(const bf16x8*)&XT[(pi * 16 + il) * 136 + ks * 32 + fo];
      yd[pi] = __builtin_amdgcn_mfma_f32_16x16x32_bf16(a, bb, yd[pi], 0, 0, 0);
    }
  }
  __syncthreads();  // all Mt reads done before Ct overwrite
  // phase4: reload full C tile into Ct (L2-hot)
#pragma unroll
  for (int j = 0; j < 4; ++j) {
    int q = tid + j * 512;
    int ll = q >> 4, n0 = (q & 15) * 8;
    *(int4*)(Ct + ll * 136 + n0) =
        *(const int4*)(xbc + (size_t)(row0 + ll) * CONV_D + INTER_D + NG * NSD + g * NSD + n0);
  }
  __syncthreads();
  // phase5: Y_off = C @ prevS^T; final write ybh = bf16(Y_diag + Y_off*exp(Acs) + D*hs)
  f32x4 yo[4];
#pragma unroll
  for (int i = 0; i < 4; ++i) yo[i] = (f32x4){0.f, 0.f, 0.f, 0.f};
#pragma unroll
  for (int ks = 0; ks < 4; ++ks) {
    bf16x8 a = *(const bf16x8*)&Ct[(wv * 16 + il) * 136 + ks * 32 + fo];
#pragma unroll
    for (int pi = 0; pi < 4; ++pi) {
      bf16x8 bb = *(const bf16x8*)&Sp[(pi * 16 + il) * 136 + ks * 32 + fo];
      yo[pi] = __builtin_amdgcn_mfma_f32_16x16x32_bf16(a, bb, yo[pi], 0, 0, 0);
    }
  }
  float dv = Dp[h];
#pragma unroll
  for (int pi = 0; pi < 4; ++pi) {
    int p = pi * 16 + il;
#pragma unroll
    for (int r = 0; r < 4; ++r) {
      int ll = wv * 16 + rl + r;
      int row = row0 + ll;
      float hsv = bf2f(xbc[(size_t)row * CONV_D + h * PD + p]);
      ybh[(size_t)row * INTER_D + h * PD + p] =
          f2bf(yd[pi][r] + yo[pi][r] * __expf(Acs[ll]) + dv * hsv);
    }
  }
}

// ---------------- F: gate silu, grouped RMSNorm (bf16 yb in) -> bf16 ----------------
__global__ __launch_bounds__(256) void fnorm_kernel(const unsigned short* __restrict__ ybh,
                                                    const unsigned short* __restrict__ proj,
                                                    const float* __restrict__ nw,
                                                    unsigned short* __restrict__ normed) {
  int row = blockIdx.x >> 3;
  int gg = blockIdx.x & 7;
  int t = threadIdx.x;
  float v[4];
  float ss = 0.f;
#pragma unroll
  for (int j = 0; j < 4; ++j) {
    int ch = gg * 1024 + j * 256 + t;
    float val = bf2f(ybh[(size_t)row * INTER_D + ch]);
    float gt = bf2f(proj[(size_t)row * PROJ_D + ch]);
    val *= gt / (1.f + __expf(-gt));
    v[j] = val;
    ss += val * val;
  }
  __shared__ float sred[256];
  sred[t] = ss;
  __syncthreads();
  for (int ofs = 128; ofs > 0; ofs >>= 1) {
    if (t < ofs) sred[t] += sred[t + ofs];
    __syncthreads();
  }
  float rms = rsqrtf(sred[0] / 1024.f + 1e-5f);
#pragma unroll
  for (int j = 0; j < 4; ++j) {
    int ch = gg * 1024 + j * 256 + t;
    normed[(size_t)row * INTER_D + ch] = f2bf(v[j] * rms * nw[ch]);
  }
}

extern "C" void kernel_launch(void* const* d_in, const int* in_sizes, int n_in,
                              void* d_out, int out_size, void* d_ws, size_t ws_size,
                              hipStream_t stream) {
  (void)in_sizes; (void)n_in; (void)out_size; (void)ws_size;
  const float* hs = (const float*)d_in[0];
  const float* w1 = (const float*)d_in[1];
  const float* cw = (const float*)d_in[2];
  const float* cb = (const float*)d_in[3];
  const float* dtb = (const float*)d_in[4];
  const float* alog = (const float*)d_in[5];
  const float* Dp = (const float*)d_in[6];
  const float* nw = (const float*)d_in[7];
  const float* w2 = (const float*)d_in[8];
  float* out = (float*)d_out;
  char* ws = (char*)d_ws;

  unsigned short* hsb = (unsigned short*)(ws);                 // 33,554,432
  unsigned short* w1b = (unsigned short*)(ws + 33554432);      // 153,092,096 (padded to 18688 rows)
  unsigned short* w2b = (unsigned short*)(ws + 186646528);     // 67,108,864
  unsigned short* proj = (unsigned short*)(ws + 253755392);    // 152,043,520
  unsigned short* xbc = (unsigned short*)(ws + 405798912);     // 83,886,080
  float* dtg = (float*)(ws + 489684992);                       // 2,097,152
  float* acsg = (float*)(ws + 491782144);                      // 2,097,152
  float* states = (float*)(ws + 493879296);                    // 134,217,728 (f32)
  unsigned short* prevs = (unsigned short*)(ws + 628097024);   // 67,108,864 (bf16)
  unsigned short* ybh = (unsigned short*)(ws + 695205888);     // 67,108,864 (bf16)
  unsigned short* normed = (unsigned short*)(ws);              // reuses hsb region (dead)

  cvt_kernel<<<dim3(16384), dim3(256), 0, stream>>>(hs, hsb, (size_t)ROWS * HIDD);
  cvt_kernel<<<dim3(74240), dim3(256), 0, stream>>>(w1, w1b, (size_t)PROJ_D * HIDD);
  cvt_kernel<<<dim3(32768), dim3(256), 0, stream>>>(w2, w2b, (size_t)HIDD * INTER_D);

  gemm256<1><<<dim3(16 * 73), dim3(512), 0, stream>>>(hsb, w1b, proj, nullptr,
                                                      PROJ_D, HIDD, HIDD, 0);
  dts_kernel<<<dim3(32), dim3(128), 0, stream>>>(proj, dtb, alog, dtg, acsg);
  conv_kernel<<<dim3(40, 4096), dim3(256), 0, stream>>>(proj, cw, cb, xbc);
  e1b_kernel<<<dim3(4096), dim3(256), 0, stream>>>(xbc, dtg, acsg, states);
  e2_kernel<<<dim3(1024), dim3(256), 0, stream>>>(acsg, states, prevs);
  e13_kernel<<<dim3(4096), dim3(512), 0, stream>>>(xbc, dtg, acsg, prevs, Dp, ybh);
  fnorm_kernel<<<dim3(32768), dim3(256), 0, stream>>>(ybh, proj, nw, normed);
  gemm256<0><<<dim3(16 * 16), dim3(512), 0, stream>>>(normed, w2b, nullptr, out,
                                                      HIDD, INTER_D, INTER_D, 0);
}

// Round 12
// 1409.756 us; speedup vs baseline: 5.7228x; 1.0186x over previous
//
#include <hip/hip_runtime.h>

#define NH 128
#define PD 64
#define NSD 128
#define NG 8
#define CHK 128
#define HIDD 4096
#define INTER_D 8192
#define CONV_D 10240
#define PROJ_D 18560
#define SEQ 2048
#define ROWS 4096
#define NCH 16

typedef __attribute__((ext_vector_type(8))) short bf16x8;
typedef __attribute__((ext_vector_type(4))) float f32x4;

__device__ __forceinline__ unsigned short f2bf(float f) {
  unsigned int u = __float_as_uint(f);
  u += 0x7FFF + ((u >> 16) & 1);
  return (unsigned short)(u >> 16);
}
__device__ __forceinline__ float bf2f(unsigned short s) {
  return __uint_as_float(((unsigned int)s) << 16);
}

__device__ __forceinline__ void gld16(const unsigned short* g, unsigned short* l) {
  __builtin_amdgcn_global_load_lds(
      (__attribute__((address_space(1))) const void*)g,
      (__attribute__((address_space(3))) void*)l, 16, 0, 0);
}

#define BAR() __builtin_amdgcn_s_barrier()
#define SCHED() __builtin_amdgcn_sched_barrier(0)
#define VMCNT(n) asm volatile("s_waitcnt vmcnt(" #n ")" ::: "memory")

// swizzled LDS fragment read: slot is a [128][64] bf16 half-tile (16KB)
__device__ __forceinline__ bf16x8 ldsfrag(const unsigned short* slot, int row, int kslot) {
  int byte = row * 128 + (((kslot ^ (row & 7)) << 4));
  return *(const bf16x8*)((const char*)slot + byte);
}

// ---------------- f32 -> bf16 convert ----------------
__global__ __launch_bounds__(256) void cvt_kernel(const float* __restrict__ in,
                                                  unsigned short* __restrict__ out,
                                                  size_t n) {
  size_t i = ((size_t)blockIdx.x * 256 + threadIdx.x) * 4;
  if (i < n) {
    float4 f = *(const float4*)(in + i);
    ushort4 o;
    o.x = f2bf(f.x); o.y = f2bf(f.y); o.z = f2bf(f.z); o.w = f2bf(f.w);
    *(ushort4*)(out + i) = o;
  }
}

// ---------------- 256^2 4-phase GEMM, BK=64 (PROVEN; do not edit) ----------------
// 8 waves (2M x 4N). Stage always into the opposite buffer (race-free).
// 608-613us on GEMM1, reproduced rounds 3/5/7/8/11. All schedule variants regressed:
// burst(R4), t+2-prefetch(R6, raced), split-K(R8), BK=32(R9/R10).
template <int OUT_BF16>
__global__ __launch_bounds__(512, 2) void gemm256(const unsigned short* __restrict__ A,
                                                  const unsigned short* __restrict__ B,
                                                  unsigned short* __restrict__ outb,
                                                  float* __restrict__ outf,
                                                  int Nreal, int Ks, int Kl, int koff) {
  __shared__ unsigned short lds[8][8192];  // 8 half-slots x 16KB = 128KB
  int tid = threadIdx.x, l = tid & 63, w = tid >> 6;
  int wm = w >> 2, wn = w & 3;
  int il = l & 15, fog = l >> 4;
  int bid = blockIdx.x;
  int xcd = bid & 7, local = bid >> 3;
  int mt = xcd * 2 + (local & 1), nt = local >> 1;
  const unsigned short* Abase = A + (size_t)mt * 256 * Ks + koff;
  const unsigned short* Bbase = B + (size_t)nt * 256 * Ks + koff;
  int NT = Kl >> 6;

  f32x4 acc[2][2][4][2];
#pragma unroll
  for (int a = 0; a < 2; ++a)
#pragma unroll
    for (int b = 0; b < 2; ++b)
#pragma unroll
      for (int m = 0; m < 4; ++m)
#pragma unroll
        for (int n = 0; n < 2; ++n) acc[a][b][m][n] = (f32x4){0.f, 0.f, 0.f, 0.f};

  auto STG = [&](int tt, int ty) {
    int tc = tt < NT ? tt : NT - 1;
    const unsigned short* g = ((ty & 1) ? Bbase : Abase) + (size_t)((ty >> 1) * 128) * Ks + tc * 64;
    unsigned short* sp = (unsigned short*)lds[(tt & 1) * 4 + ty];
#pragma unroll
    for (int j = 0; j < 2; ++j) {
      int row = (j * 8 + w) * 8 + (l >> 3);
      int scol = ((l & 7) ^ (row & 7)) * 8;  // inverse-swizzled global source
      gld16(g + (size_t)row * Ks + scol, sp + (j * 8 + w) * 512);
    }
  };

#define LDA(SLOT)                                          \
  _Pragma("unroll") for (int mi = 0; mi < 4; ++mi)         \
  _Pragma("unroll") for (int kk = 0; kk < 2; ++kk)         \
      av[mi][kk] = ldsfrag(SLOT, wm * 64 + mi * 16 + il, kk * 4 + fog);
#define LDB(QN, SLOT)                                      \
  _Pragma("unroll") for (int ni = 0; ni < 2; ++ni)         \
  _Pragma("unroll") for (int kk = 0; kk < 2; ++kk)         \
      bv[QN][ni][kk] = ldsfrag(SLOT, wn * 32 + ni * 16 + il, kk * 4 + fog);
#define MFMA_PH(QM, QN)                                    \
  _Pragma("unroll") for (int mi = 0; mi < 4; ++mi)         \
  _Pragma("unroll") for (int ni = 0; ni < 2; ++ni)         \
  _Pragma("unroll") for (int kk = 0; kk < 2; ++kk)         \
      acc[QM][QN][mi][ni] = __builtin_amdgcn_mfma_f32_16x16x32_bf16( \
          av[mi][kk], bv[QN][ni][kk], acc[QM][QN][mi][ni], 0, 0, 0);

  // prologue: tile0 all 4 halves; leave A1 (ty2) in flight
  STG(0, 0); STG(0, 1); STG(0, 3); STG(0, 2);
  VMCNT(2);
  BAR(); SCHED();

  for (int t = 0; t < NT; ++t) {
    const unsigned short* sA0 = lds[(t & 1) * 4 + 0];
    const unsigned short* sB0 = lds[(t & 1) * 4 + 1];
    const unsigned short* sA1 = lds[(t & 1) * 4 + 2];
    const unsigned short* sB1 = lds[(t & 1) * 4 + 3];
    bf16x8 av[4][2], bv[2][2][2];
    // P1: read A0 + both B quadrants; stage A0,B0 of t+1
    LDA(sA0); LDB(0, sB0); LDB(1, sB1);
    STG(t + 1, 0); STG(t + 1, 1);
    BAR();
    __builtin_amdgcn_s_setprio(1);
    MFMA_PH(0, 0);
    __builtin_amdgcn_s_setprio(0);
    VMCNT(4);  // A1(t) landed (staged prev iter) -> safe for P3 reads
    BAR(); SCHED();
    // P2: pure MFMA; stage B1 of t+1
    STG(t + 1, 3);
    __builtin_amdgcn_s_setprio(1);
    MFMA_PH(0, 1);
    __builtin_amdgcn_s_setprio(0);
    BAR();
    // P3: read A1; stage A1 of t+1
    LDA(sA1);
    STG(t + 1, 2);
    BAR();
    __builtin_amdgcn_s_setprio(1);
    MFMA_PH(1, 0);
    __builtin_amdgcn_s_setprio(0);
    BAR();
    // P4: pure MFMA
    __builtin_amdgcn_s_setprio(1);
    MFMA_PH(1, 1);
    __builtin_amdgcn_s_setprio(0);
    VMCNT(2);  // A0,B0,B1(t+1) landed -> safe for next P1 reads
    BAR(); SCHED();
  }
  VMCNT(0);

  // epilogue: C write
  int rl = (l >> 4) * 4;
#pragma unroll
  for (int qm = 0; qm < 2; ++qm)
#pragma unroll
    for (int qn = 0; qn < 2; ++qn)
#pragma unroll
      for (int mi = 0; mi < 4; ++mi)
#pragma unroll
        for (int ni = 0; ni < 2; ++ni) {
          int grow = mt * 256 + qm * 128 + wm * 64 + mi * 16 + rl;
          int gcol = nt * 256 + qn * 128 + wn * 32 + ni * 16 + il;
          if (!OUT_BF16 || gcol < Nreal) {
#pragma unroll
            for (int r = 0; r < 4; ++r) {
              float v = acc[qm][qn][mi][ni][r];
              if (OUT_BF16)
                outb[(size_t)(grow + r) * Nreal + gcol] = f2bf(v);
              else
                outf[(size_t)(grow + r) * Nreal + gcol] = v;
            }
          }
        }
#undef LDA
#undef LDB
#undef MFMA_PH
}

// ---------------- dt softplus + A*dt cumsum ----------------
__global__ __launch_bounds__(128) void dts_kernel(const unsigned short* __restrict__ proj,
                                                  const float* __restrict__ dt_bias,
                                                  const float* __restrict__ A_log,
                                                  float* __restrict__ dtg,
                                                  float* __restrict__ acsg) {
  int bc = blockIdx.x;
  int h = threadIdx.x;
  int b = bc >> 4, c = bc & 15;
  float A = -__expf(A_log[h]);
  float bias = dt_bias[h];
  float cum = 0.f;
  int row0 = b * SEQ + c * CHK;
#pragma unroll 4
  for (int ll = 0; ll < CHK; ++ll) {
    float x = bf2f(proj[(size_t)(row0 + ll) * PROJ_D + (PROJ_D - NH) + h]) + bias;
    float d = (x > 20.f) ? x : log1pf(expf(x));
    dtg[(size_t)(row0 + ll) * NH + h] = d;
    cum += A * d;
    acsg[(((size_t)bc * NH) + h) * CHK + ll] = cum;
  }
}

// ---------------- causal depthwise conv + bias + silu ----------------
__global__ __launch_bounds__(256) void conv_kernel(const unsigned short* __restrict__ proj,
                                                   const float* __restrict__ cw,
                                                   const float* __restrict__ cb,
                                                   unsigned short* __restrict__ xbc) {
  int ch = blockIdx.x * 256 + threadIdx.x;
  int row = blockIdx.y;
  int b = row >> 11, ll = row & 2047;
  float acc = cb[ch];
#pragma unroll
  for (int k = 0; k < 4; ++k) {
    int l2 = ll - 3 + k;
    if (l2 >= 0)
      acc += bf2f(proj[(size_t)(b * SEQ + l2) * PROJ_D + INTER_D + ch]) * cw[ch * 4 + k];
  }
  float s = acc / (1.f + __expf(-acc));
  xbc[(size_t)row * CONV_D + ch] = f2bf(s);
}

// ---------------- E1b: states = X^T @ B_decay (bf16 out) ----------------
__global__ __launch_bounds__(256) void e1b_kernel(const unsigned short* __restrict__ xbc,
                                                  const float* __restrict__ dtg,
                                                  const float* __restrict__ acsg,
                                                  unsigned short* __restrict__ states16) {
  int bid = blockIdx.x;
  int h = bid & 127, c = (bid >> 7) & 15, b = bid >> 11;
  int g = h & 7;
  int row0 = b * SEQ + c * CHK;
  __shared__ __align__(16) char smem[52736];
  unsigned short* XT = (unsigned short*)smem;
  unsigned short* BdT = (unsigned short*)(smem + 17408);
  float* Acs = (float*)(smem + 52224);
  int tid = threadIdx.x, lane = tid & 63, wv = tid >> 6;
  int fo = (lane >> 4) * 8, il = lane & 15, rl = (lane >> 4) * 4;
  if (tid < 128) Acs[tid] = acsg[(((size_t)(b * NCH + c) * NH) + h) * CHK + tid];
  __syncthreads();
#pragma unroll
  for (int j = 0; j < 4; ++j) {
    int q = tid + j * 256;
    int ll = q >> 3, p0 = (q & 7) * 8;
    int row = row0 + ll;
    float dtv = dtg[(size_t)row * NH + h];
    int4 raw = *(const int4*)(xbc + (size_t)row * CONV_D + h * PD + p0);
    unsigned short* u = (unsigned short*)&raw;
#pragma unroll
    for (int e = 0; e < 8; ++e) XT[(p0 + e) * 136 + ll] = f2bf(bf2f(u[e]) * dtv);
  }
#pragma unroll
  for (int j = 0; j < 8; ++j) {
    int q = tid + j * 256;
    int ll = q >> 4, n0 = (q & 15) * 8;
    float dec = __expf(Acs[CHK - 1] - Acs[ll]);
    int4 raw = *(const int4*)(xbc + (size_t)(row0 + ll) * CONV_D + INTER_D + g * NSD + n0);
    unsigned short* u = (unsigned short*)&raw;
#pragma unroll
    for (int e = 0; e < 8; ++e) BdT[(n0 + e) * 136 + ll] = f2bf(bf2f(u[e]) * dec);
  }
  __syncthreads();
  f32x4 st[8];
#pragma unroll
  for (int i = 0; i < 8; ++i) st[i] = (f32x4){0.f, 0.f, 0.f, 0.f};
#pragma unroll
  for (int ks = 0; ks < 4; ++ks) {
    bf16x8 a = *(const bf16x8*)&XT[(wv * 16 + il) * 136 + ks * 32 + fo];
#pragma unroll
    for (int ni = 0; ni < 8; ++ni) {
      bf16x8 bb = *(const bf16x8*)&BdT[(ni * 16 + il) * 136 + ks * 32 + fo];
      st[ni] = __builtin_amdgcn_mfma_f32_16x16x32_bf16(a, bb, st[ni], 0, 0, 0);
    }
  }
  size_t base = ((size_t)(b * NH + h) * NCH + c) * (PD * NSD);
#pragma unroll
  for (int ni = 0; ni < 8; ++ni) {
    int n = ni * 16 + il;
#pragma unroll
    for (int r = 0; r < 4; ++r) {
      int p = wv * 16 + rl + r;
      states16[base + p * NSD + n] = f2bf(st[ni][r]);
    }
  }
}

// ---------------- E2: chunk-state scan (bf16 in, f32 accum, bf16 prevs out) ----------------
__global__ __launch_bounds__(256) void e2_kernel(const float* __restrict__ acsg,
                                                 const unsigned short* __restrict__ states16,
                                                 unsigned short* __restrict__ prevs) {
  int bid = blockIdx.x;          // (b*128+h)*4 + pg
  int bh = bid >> 2, pg = bid & 3;
  int b = bh >> 7;
  int t = threadIdx.x;
  float S[8];
#pragma unroll
  for (int j = 0; j < 8; ++j) S[j] = 0.f;
  for (int c = 0; c < NCH; ++c) {
    float alast = acsg[(((size_t)((b * NCH + c) * NH) + (bh & 127))) * CHK + (CHK - 1)];
    float dec = __expf(alast);
    size_t base = ((size_t)bh * NCH + c) * (PD * NSD) + (size_t)pg * 2048;
#pragma unroll
    for (int j = 0; j < 8; ++j) {
      size_t e = base + (size_t)j * 256 + t;
      float v = bf2f(states16[e]);
      prevs[e] = f2bf(S[j]);
      S[j] = S[j] * dec + v;
    }
  }
}

// ---------------- E13: fused Y_diag + Y_off + D_res -> yb (bf16 out) ----------------
// phase1's per-wave C fragments are saved in registers (cf[kc]) and reused as
// phase5's A-operand (identical row/col coverage) -> no phase4 C reload, 2 fewer barriers.
__global__ __launch_bounds__(512) void e13_kernel(const unsigned short* __restrict__ xbc,
                                                  const float* __restrict__ dtg,
                                                  const float* __restrict__ acsg,
                                                  const unsigned short* __restrict__ prevs,
                                                  const float* __restrict__ Dp,
                                                  unsigned short* __restrict__ ybh) {
  int bid = blockIdx.x;
  int h = bid & 127, c = (bid >> 7) & 15, b = bid >> 11;
  int g = h & 7;
  int row0 = b * SEQ + c * CHK;
  __shared__ __align__(16) char smem[70144];
  unsigned short* Cst = (unsigned short*)smem;            // [128][40] Gm phase
  unsigned short* Bst = (unsigned short*)(smem + 10240);  // [128][40] Gm phase
  unsigned short* Mt = (unsigned short*)smem;             // [128][136]
  unsigned short* XT = (unsigned short*)(smem + 34816);   // [64][136]
  unsigned short* Sp = (unsigned short*)(smem + 52224);   // [64][136]
  float* Acs = (float*)(smem + 69632);                    // [128]
  int tid = threadIdx.x, lane = tid & 63, wv = tid >> 6;  // 8 waves
  int fo = (lane >> 4) * 8, il = lane & 15, rl = (lane >> 4) * 4;
  if (tid < 128) Acs[tid] = acsg[(((size_t)(b * NCH + c) * NH) + h) * CHK + tid];

  // phase1: Gm = C @ B^T ; save per-wave C fragments for phase5
  f32x4 gm[8];
#pragma unroll
  for (int i = 0; i < 8; ++i) gm[i] = (f32x4){0.f, 0.f, 0.f, 0.f};
  bf16x8 cf[4];
  int srow = tid >> 2, scol = (tid & 3) * 8;
#pragma unroll
  for (int kc = 0; kc < 4; ++kc) {
    __syncthreads();
    *(int4*)(Cst + srow * 40 + scol) =
        *(const int4*)(xbc + (size_t)(row0 + srow) * CONV_D + INTER_D + NG * NSD + g * NSD + kc * 32 + scol);
    *(int4*)(Bst + srow * 40 + scol) =
        *(const int4*)(xbc + (size_t)(row0 + srow) * CONV_D + INTER_D + g * NSD + kc * 32 + scol);
    __syncthreads();
    bf16x8 a = *(const bf16x8*)&Cst[(wv * 16 + il) * 40 + fo];
    cf[kc] = a;
#pragma unroll
    for (int ni = 0; ni < 8; ++ni) {
      bf16x8 bb = *(const bf16x8*)&Bst[(ni * 16 + il) * 40 + fo];
      gm[ni] = __builtin_amdgcn_mfma_f32_16x16x32_bf16(a, bb, gm[ni], 0, 0, 0);
    }
  }
  __syncthreads();
  // phase2: masked+decayed M -> Mt; stage XT = (hs*dt)^T; stage Sp = prevs (bf16 copy)
#pragma unroll
  for (int ni = 0; ni < 8; ++ni) {
    int s = ni * 16 + il;
#pragma unroll
    for (int r = 0; r < 4; ++r) {
      int ll = wv * 16 + rl + r;
      float v = (s <= ll) ? gm[ni][r] * __expf(Acs[ll] - Acs[s]) : 0.f;
      Mt[ll * 136 + s] = f2bf(v);
    }
  }
#pragma unroll
  for (int j = 0; j < 2; ++j) {
    int q = tid + j * 512;
    int ll = q >> 3, p0 = (q & 7) * 8;
    int row = row0 + ll;
    float dtv = dtg[(size_t)row * NH + h];
    int4 raw = *(const int4*)(xbc + (size_t)row * CONV_D + h * PD + p0);
    unsigned short* u = (unsigned short*)&raw;
#pragma unroll
    for (int e = 0; e < 8; ++e) XT[(p0 + e) * 136 + ll] = f2bf(bf2f(u[e]) * dtv);
  }
  size_t sbase = ((size_t)(b * NH + h) * NCH + c) * (PD * NSD);
#pragma unroll
  for (int j = 0; j < 2; ++j) {
    int q = tid + j * 512;
    int p = q >> 4, n0 = (q & 15) * 8;
    *(int4*)(Sp + p * 136 + n0) = *(const int4*)(prevs + sbase + p * NSD + n0);
  }
  __syncthreads();
  // phase3: Y_diag = M @ X ; phase5 fused: Y_off = cf @ Sp^T (registers, no reload)
  f32x4 yd[4], yo[4];
#pragma unroll
  for (int i = 0; i < 4; ++i) {
    yd[i] = (f32x4){0.f, 0.f, 0.f, 0.f};
    yo[i] = (f32x4){0.f, 0.f, 0.f, 0.f};
  }
#pragma unroll
  for (int ks = 0; ks < 4; ++ks) {
    bf16x8 a = *(const bf16x8*)&Mt[(wv * 16 + il) * 136 + ks * 32 + fo];
#pragma unroll
    for (int pi = 0; pi < 4; ++pi) {
      bf16x8 bb = *(const bf16x8*)&XT[(pi * 16 + il) * 136 + ks * 32 + fo];
      bf16x8 sb = *(const bf16x8*)&Sp[(pi * 16 + il) * 136 + ks * 32 + fo];
      yd[pi] = __builtin_amdgcn_mfma_f32_16x16x32_bf16(a, bb, yd[pi], 0, 0, 0);
      yo[pi] = __builtin_amdgcn_mfma_f32_16x16x32_bf16(cf[ks], sb, yo[pi], 0, 0, 0);
    }
  }
  float dv = Dp[h];
#pragma unroll
  for (int pi = 0; pi < 4; ++pi) {
    int p = pi * 16 + il;
#pragma unroll
    for (int r = 0; r < 4; ++r) {
      int ll = wv * 16 + rl + r;
      int row = row0 + ll;
      float hsv = bf2f(xbc[(size_t)row * CONV_D + h * PD + p]);
      ybh[(size_t)row * INTER_D + h * PD + p] =
          f2bf(yd[pi][r] + yo[pi][r] * __expf(Acs[ll]) + dv * hsv);
    }
  }
}

// ---------------- F: gate silu, grouped RMSNorm (bf16 yb in) -> bf16 ----------------
__global__ __launch_bounds__(256) void fnorm_kernel(const unsigned short* __restrict__ ybh,
                                                    const unsigned short* __restrict__ proj,
                                                    const float* __restrict__ nw,
                                                    unsigned short* __restrict__ normed) {
  int row = blockIdx.x >> 3;
  int gg = blockIdx.x & 7;
  int t = threadIdx.x;
  float v[4];
  float ss = 0.f;
#pragma unroll
  for (int j = 0; j < 4; ++j) {
    int ch = gg * 1024 + j * 256 + t;
    float val = bf2f(ybh[(size_t)row * INTER_D + ch]);
    float gt = bf2f(proj[(size_t)row * PROJ_D + ch]);
    val *= gt / (1.f + __expf(-gt));
    v[j] = val;
    ss += val * val;
  }
  __shared__ float sred[256];
  sred[t] = ss;
  __syncthreads();
  for (int ofs = 128; ofs > 0; ofs >>= 1) {
    if (t < ofs) sred[t] += sred[t + ofs];
    __syncthreads();
  }
  float rms = rsqrtf(sred[0] / 1024.f + 1e-5f);
#pragma unroll
  for (int j = 0; j < 4; ++j) {
    int ch = gg * 1024 + j * 256 + t;
    normed[(size_t)row * INTER_D + ch] = f2bf(v[j] * rms * nw[ch]);
  }
}

extern "C" void kernel_launch(void* const* d_in, const int* in_sizes, int n_in,
                              void* d_out, int out_size, void* d_ws, size_t ws_size,
                              hipStream_t stream) {
  (void)in_sizes; (void)n_in; (void)out_size; (void)ws_size;
  const float* hs = (const float*)d_in[0];
  const float* w1 = (const float*)d_in[1];
  const float* cw = (const float*)d_in[2];
  const float* cb = (const float*)d_in[3];
  const float* dtb = (const float*)d_in[4];
  const float* alog = (const float*)d_in[5];
  const float* Dp = (const float*)d_in[6];
  const float* nw = (const float*)d_in[7];
  const float* w2 = (const float*)d_in[8];
  float* out = (float*)d_out;
  char* ws = (char*)d_ws;

  unsigned short* hsb = (unsigned short*)(ws);                 // 33,554,432
  unsigned short* w1b = (unsigned short*)(ws + 33554432);      // 153,092,096 (padded to 18688 rows)
  unsigned short* w2b = (unsigned short*)(ws + 186646528);     // 67,108,864
  unsigned short* proj = (unsigned short*)(ws + 253755392);    // 152,043,520
  unsigned short* xbc = (unsigned short*)(ws + 405798912);     // 83,886,080
  float* dtg = (float*)(ws + 489684992);                       // 2,097,152
  float* acsg = (float*)(ws + 491782144);                      // 2,097,152
  unsigned short* states16 = (unsigned short*)(ws + 493879296);// 67,108,864 (bf16)
  unsigned short* prevs = (unsigned short*)(ws + 560988160);   // 67,108,864 (bf16)
  unsigned short* ybh = (unsigned short*)(ws + 628097024);     // 67,108,864 (bf16)
  unsigned short* normed = (unsigned short*)(ws);              // reuses hsb region (dead)

  cvt_kernel<<<dim3(16384), dim3(256), 0, stream>>>(hs, hsb, (size_t)ROWS * HIDD);
  cvt_kernel<<<dim3(74240), dim3(256), 0, stream>>>(w1, w1b, (size_t)PROJ_D * HIDD);
  cvt_kernel<<<dim3(32768), dim3(256), 0, stream>>>(w2, w2b, (size_t)HIDD * INTER_D);

  gemm256<1><<<dim3(16 * 73), dim3(512), 0, stream>>>(hsb, w1b, proj, nullptr,
                                                      PROJ_D, HIDD, HIDD, 0);
  dts_kernel<<<dim3(32), dim3(128), 0, stream>>>(proj, dtb, alog, dtg, acsg);
  conv_kernel<<<dim3(40, 4096), dim3(256), 0, stream>>>(proj, cw, cb, xbc);
  e1b_kernel<<<dim3(4096), dim3(256), 0, stream>>>(xbc, dtg, acsg, states16);
  e2_kernel<<<dim3(1024), dim3(256), 0, stream>>>(acsg, states16, prevs);
  e13_kernel<<<dim3(4096), dim3(512), 0, stream>>>(xbc, dtg, acsg, prevs, Dp, ybh);
  fnorm_kernel<<<dim3(32768), dim3(256), 0, stream>>>(ybh, proj, nw, normed);
  gemm256<0><<<dim3(16 * 16), dim3(512), 0, stream>>>(normed, w2b, nullptr, out,
                                                      HIDD, INTER_D, INTER_D, 0);
}

// Round 13
// 1375.755 us; speedup vs baseline: 5.8642x; 1.0247x over previous
//
#include <hip/hip_runtime.h>

#define NH 128
#define PD 64
#define NSD 128
#define NG 8
#define CHK 128
#define HIDD 4096
#define INTER_D 8192
#define CONV_D 10240
#define PROJ_D 18560
#define SEQ 2048
#define ROWS 4096
#define NCH 16

typedef __attribute__((ext_vector_type(8))) short bf16x8;
typedef __attribute__((ext_vector_type(4))) float f32x4;

__device__ __forceinline__ unsigned short f2bf(float f) {
  unsigned int u = __float_as_uint(f);
  u += 0x7FFF + ((u >> 16) & 1);
  return (unsigned short)(u >> 16);
}
__device__ __forceinline__ float bf2f(unsigned short s) {
  return __uint_as_float(((unsigned int)s) << 16);
}

__device__ __forceinline__ void gld16(const unsigned short* g, unsigned short* l) {
  __builtin_amdgcn_global_load_lds(
      (__attribute__((address_space(1))) const void*)g,
      (__attribute__((address_space(3))) void*)l, 16, 0, 0);
}

#define BAR() __builtin_amdgcn_s_barrier()
#define SCHED() __builtin_amdgcn_sched_barrier(0)
#define VMCNT(n) asm volatile("s_waitcnt vmcnt(" #n ")" ::: "memory")

// swizzled LDS fragment read: slot is a [128][64] bf16 half-tile (16KB)
__device__ __forceinline__ bf16x8 ldsfrag(const unsigned short* slot, int row, int kslot) {
  int byte = row * 128 + (((kslot ^ (row & 7)) << 4));
  return *(const bf16x8*)((const char*)slot + byte);
}

// ---------------- f32 -> bf16 convert ----------------
__global__ __launch_bounds__(256) void cvt_kernel(const float* __restrict__ in,
                                                  unsigned short* __restrict__ out,
                                                  size_t n) {
  size_t i = ((size_t)blockIdx.x * 256 + threadIdx.x) * 4;
  if (i < n) {
    float4 f = *(const float4*)(in + i);
    ushort4 o;
    o.x = f2bf(f.x); o.y = f2bf(f.y); o.z = f2bf(f.z); o.w = f2bf(f.w);
    *(ushort4*)(out + i) = o;
  }
}

// ---------------- 256^2 4-phase GEMM, BK=64 (PROVEN; do not edit) ----------------
// 8 waves (2M x 4N). Stage always into the opposite buffer (race-free).
// 608-614us on GEMM1, reproduced rounds 3/5/7/8/11/12. All schedule variants regressed:
// burst(R4), t+2-prefetch(R6, raced), split-K(R8), BK=32(R9/R10).
template <int OUT_BF16>
__global__ __launch_bounds__(512, 2) void gemm256(const unsigned short* __restrict__ A,
                                                  const unsigned short* __restrict__ B,
                                                  unsigned short* __restrict__ outb,
                                                  float* __restrict__ outf,
                                                  int Nreal, int Ks, int Kl, int koff) {
  __shared__ unsigned short lds[8][8192];  // 8 half-slots x 16KB = 128KB
  int tid = threadIdx.x, l = tid & 63, w = tid >> 6;
  int wm = w >> 2, wn = w & 3;
  int il = l & 15, fog = l >> 4;
  int bid = blockIdx.x;
  int xcd = bid & 7, local = bid >> 3;
  int mt = xcd * 2 + (local & 1), nt = local >> 1;
  const unsigned short* Abase = A + (size_t)mt * 256 * Ks + koff;
  const unsigned short* Bbase = B + (size_t)nt * 256 * Ks + koff;
  int NT = Kl >> 6;

  f32x4 acc[2][2][4][2];
#pragma unroll
  for (int a = 0; a < 2; ++a)
#pragma unroll
    for (int b = 0; b < 2; ++b)
#pragma unroll
      for (int m = 0; m < 4; ++m)
#pragma unroll
        for (int n = 0; n < 2; ++n) acc[a][b][m][n] = (f32x4){0.f, 0.f, 0.f, 0.f};

  auto STG = [&](int tt, int ty) {
    int tc = tt < NT ? tt : NT - 1;
    const unsigned short* g = ((ty & 1) ? Bbase : Abase) + (size_t)((ty >> 1) * 128) * Ks + tc * 64;
    unsigned short* sp = (unsigned short*)lds[(tt & 1) * 4 + ty];
#pragma unroll
    for (int j = 0; j < 2; ++j) {
      int row = (j * 8 + w) * 8 + (l >> 3);
      int scol = ((l & 7) ^ (row & 7)) * 8;  // inverse-swizzled global source
      gld16(g + (size_t)row * Ks + scol, sp + (j * 8 + w) * 512);
    }
  };

#define LDA(SLOT)                                          \
  _Pragma("unroll") for (int mi = 0; mi < 4; ++mi)         \
  _Pragma("unroll") for (int kk = 0; kk < 2; ++kk)         \
      av[mi][kk] = ldsfrag(SLOT, wm * 64 + mi * 16 + il, kk * 4 + fog);
#define LDB(QN, SLOT)                                      \
  _Pragma("unroll") for (int ni = 0; ni < 2; ++ni)         \
  _Pragma("unroll") for (int kk = 0; kk < 2; ++kk)         \
      bv[QN][ni][kk] = ldsfrag(SLOT, wn * 32 + ni * 16 + il, kk * 4 + fog);
#define MFMA_PH(QM, QN)                                    \
  _Pragma("unroll") for (int mi = 0; mi < 4; ++mi)         \
  _Pragma("unroll") for (int ni = 0; ni < 2; ++ni)         \
  _Pragma("unroll") for (int kk = 0; kk < 2; ++kk)         \
      acc[QM][QN][mi][ni] = __builtin_amdgcn_mfma_f32_16x16x32_bf16( \
          av[mi][kk], bv[QN][ni][kk], acc[QM][QN][mi][ni], 0, 0, 0);

  // prologue: tile0 all 4 halves; leave A1 (ty2) in flight
  STG(0, 0); STG(0, 1); STG(0, 3); STG(0, 2);
  VMCNT(2);
  BAR(); SCHED();

  for (int t = 0; t < NT; ++t) {
    const unsigned short* sA0 = lds[(t & 1) * 4 + 0];
    const unsigned short* sB0 = lds[(t & 1) * 4 + 1];
    const unsigned short* sA1 = lds[(t & 1) * 4 + 2];
    const unsigned short* sB1 = lds[(t & 1) * 4 + 3];
    bf16x8 av[4][2], bv[2][2][2];
    // P1: read A0 + both B quadrants; stage A0,B0 of t+1
    LDA(sA0); LDB(0, sB0); LDB(1, sB1);
    STG(t + 1, 0); STG(t + 1, 1);
    BAR();
    __builtin_amdgcn_s_setprio(1);
    MFMA_PH(0, 0);
    __builtin_amdgcn_s_setprio(0);
    VMCNT(4);  // A1(t) landed (staged prev iter) -> safe for P3 reads
    BAR(); SCHED();
    // P2: pure MFMA; stage B1 of t+1
    STG(t + 1, 3);
    __builtin_amdgcn_s_setprio(1);
    MFMA_PH(0, 1);
    __builtin_amdgcn_s_setprio(0);
    BAR();
    // P3: read A1; stage A1 of t+1
    LDA(sA1);
    STG(t + 1, 2);
    BAR();
    __builtin_amdgcn_s_setprio(1);
    MFMA_PH(1, 0);
    __builtin_amdgcn_s_setprio(0);
    BAR();
    // P4: pure MFMA
    __builtin_amdgcn_s_setprio(1);
    MFMA_PH(1, 1);
    __builtin_amdgcn_s_setprio(0);
    VMCNT(2);  // A0,B0,B1(t+1) landed -> safe for next P1 reads
    BAR(); SCHED();
  }
  VMCNT(0);

  // epilogue: C write
  int rl = (l >> 4) * 4;
#pragma unroll
  for (int qm = 0; qm < 2; ++qm)
#pragma unroll
    for (int qn = 0; qn < 2; ++qn)
#pragma unroll
      for (int mi = 0; mi < 4; ++mi)
#pragma unroll
        for (int ni = 0; ni < 2; ++ni) {
          int grow = mt * 256 + qm * 128 + wm * 64 + mi * 16 + rl;
          int gcol = nt * 256 + qn * 128 + wn * 32 + ni * 16 + il;
          if (!OUT_BF16 || gcol < Nreal) {
#pragma unroll
            for (int r = 0; r < 4; ++r) {
              float v = acc[qm][qn][mi][ni][r];
              if (OUT_BF16)
                outb[(size_t)(grow + r) * Nreal + gcol] = f2bf(v);
              else
                outf[(size_t)(grow + r) * Nreal + gcol] = v;
            }
          }
        }
#undef LDA
#undef LDB
#undef MFMA_PH
}

// ---------------- dt softplus + A*dt cumsum ----------------
__global__ __launch_bounds__(128) void dts_kernel(const unsigned short* __restrict__ proj,
                                                  const float* __restrict__ dt_bias,
                                                  const float* __restrict__ A_log,
                                                  float* __restrict__ dtg,
                                                  float* __restrict__ acsg) {
  int bc = blockIdx.x;
  int h = threadIdx.x;
  int b = bc >> 4, c = bc & 15;
  float A = -__expf(A_log[h]);
  float bias = dt_bias[h];
  float cum = 0.f;
  int row0 = b * SEQ + c * CHK;
#pragma unroll 4
  for (int ll = 0; ll < CHK; ++ll) {
    float x = bf2f(proj[(size_t)(row0 + ll) * PROJ_D + (PROJ_D - NH) + h]) + bias;
    float d = (x > 20.f) ? x : log1pf(expf(x));
    dtg[(size_t)(row0 + ll) * NH + h] = d;
    cum += A * d;
    acsg[(((size_t)bc * NH) + h) * CHK + ll] = cum;
  }
}

// ---------------- causal depthwise conv + bias + silu (8-wide vectorized) ----------------
__global__ __launch_bounds__(256) void conv_kernel(const unsigned short* __restrict__ proj,
                                                   const float* __restrict__ cw,
                                                   const float* __restrict__ cb,
                                                   unsigned short* __restrict__ xbc) {
  int ch0 = (blockIdx.x * 256 + threadIdx.x) * 8;  // grid.x = 5 -> 10240 channels
  int row = blockIdx.y;
  int b = row >> 11, ll = row & 2047;
  float4 cwv[8];
#pragma unroll
  for (int e = 0; e < 8; ++e) cwv[e] = *(const float4*)(cw + (ch0 + e) * 4);
  float acc[8];
#pragma unroll
  for (int e = 0; e < 8; ++e) acc[e] = cb[ch0 + e];
#pragma unroll
  for (int k = 0; k < 4; ++k) {
    int l2 = ll - 3 + k;
    if (l2 >= 0) {
      bf16x8 v = *(const bf16x8*)(proj + (size_t)(b * SEQ + l2) * PROJ_D + INTER_D + ch0);
#pragma unroll
      for (int e = 0; e < 8; ++e)
        acc[e] += bf2f(((unsigned short*)&v)[e]) * ((const float*)&cwv[e])[k];
    }
  }
  unsigned short o[8];
#pragma unroll
  for (int e = 0; e < 8; ++e) {
    float s = acc[e] / (1.f + __expf(-acc[e]));
    o[e] = f2bf(s);
  }
  *(int4*)(xbc + (size_t)row * CONV_D + ch0) = *(int4*)o;
}

// ---------------- E1b: states = X^T @ B_decay (bf16 out) ----------------
__global__ __launch_bounds__(256) void e1b_kernel(const unsigned short* __restrict__ xbc,
                                                  const float* __restrict__ dtg,
                                                  const float* __restrict__ acsg,
                                                  unsigned short* __restrict__ states16) {
  int bid = blockIdx.x;
  int h = bid & 127, c = (bid >> 7) & 15, b = bid >> 11;
  int g = h & 7;
  int row0 = b * SEQ + c * CHK;
  __shared__ __align__(16) char smem[52736];
  unsigned short* XT = (unsigned short*)smem;
  unsigned short* BdT = (unsigned short*)(smem + 17408);
  float* Acs = (float*)(smem + 52224);
  int tid = threadIdx.x, lane = tid & 63, wv = tid >> 6;
  int fo = (lane >> 4) * 8, il = lane & 15, rl = (lane >> 4) * 4;
  if (tid < 128) Acs[tid] = acsg[(((size_t)(b * NCH + c) * NH) + h) * CHK + tid];
  __syncthreads();
#pragma unroll
  for (int j = 0; j < 4; ++j) {
    int q = tid + j * 256;
    int ll = q >> 3, p0 = (q & 7) * 8;
    int row = row0 + ll;
    float dtv = dtg[(size_t)row * NH + h];
    int4 raw = *(const int4*)(xbc + (size_t)row * CONV_D + h * PD + p0);
    unsigned short* u = (unsigned short*)&raw;
#pragma unroll
    for (int e = 0; e < 8; ++e) XT[(p0 + e) * 136 + ll] = f2bf(bf2f(u[e]) * dtv);
  }
#pragma unroll
  for (int j = 0; j < 8; ++j) {
    int q = tid + j * 256;
    int ll = q >> 4, n0 = (q & 15) * 8;
    float dec = __expf(Acs[CHK - 1] - Acs[ll]);
    int4 raw = *(const int4*)(xbc + (size_t)(row0 + ll) * CONV_D + INTER_D + g * NSD + n0);
    unsigned short* u = (unsigned short*)&raw;
#pragma unroll
    for (int e = 0; e < 8; ++e) BdT[(n0 + e) * 136 + ll] = f2bf(bf2f(u[e]) * dec);
  }
  __syncthreads();
  f32x4 st[8];
#pragma unroll
  for (int i = 0; i < 8; ++i) st[i] = (f32x4){0.f, 0.f, 0.f, 0.f};
#pragma unroll
  for (int ks = 0; ks < 4; ++ks) {
    bf16x8 a = *(const bf16x8*)&XT[(wv * 16 + il) * 136 + ks * 32 + fo];
#pragma unroll
    for (int ni = 0; ni < 8; ++ni) {
      bf16x8 bb = *(const bf16x8*)&BdT[(ni * 16 + il) * 136 + ks * 32 + fo];
      st[ni] = __builtin_amdgcn_mfma_f32_16x16x32_bf16(a, bb, st[ni], 0, 0, 0);
    }
  }
  size_t base = ((size_t)(b * NH + h) * NCH + c) * (PD * NSD);
#pragma unroll
  for (int ni = 0; ni < 8; ++ni) {
    int n = ni * 16 + il;
#pragma unroll
    for (int r = 0; r < 4; ++r) {
      int p = wv * 16 + rl + r;
      states16[base + p * NSD + n] = f2bf(st[ni][r]);
    }
  }
}

// ---------------- E2: chunk-state scan (bf16x8 per thread, f32 accum) ----------------
__global__ __launch_bounds__(256) void e2_kernel(const float* __restrict__ acsg,
                                                 const unsigned short* __restrict__ states16,
                                                 unsigned short* __restrict__ prevs) {
  int bid = blockIdx.x;          // (b*128+h)*4 + pg
  int bh = bid >> 2, pg = bid & 3;
  int b = bh >> 7;
  int t = threadIdx.x;
  float S[8];
#pragma unroll
  for (int j = 0; j < 8; ++j) S[j] = 0.f;
  for (int c = 0; c < NCH; ++c) {
    float alast = acsg[(((size_t)((b * NCH + c) * NH) + (bh & 127))) * CHK + (CHK - 1)];
    float dec = __expf(alast);
    size_t base = ((size_t)bh * NCH + c) * (PD * NSD) + (size_t)pg * 2048 + (size_t)t * 8;
    bf16x8 v = *(const bf16x8*)(states16 + base);
    unsigned short o[8];
#pragma unroll
    for (int j = 0; j < 8; ++j) {
      o[j] = f2bf(S[j]);
      S[j] = S[j] * dec + bf2f(((unsigned short*)&v)[j]);
    }
    *(bf16x8*)(prevs + base) = *(bf16x8*)o;
  }
}

// ---------------- E13: fused Y_diag + Y_off + D_res -> yb (bf16 out) ----------------
// phase1's per-wave C fragments saved in registers (cf[kc]) and reused as phase5's
// A-operand (identical coverage) -> no phase4 C reload, 2 fewer barriers.
__global__ __launch_bounds__(512) void e13_kernel(const unsigned short* __restrict__ xbc,
                                                  const float* __restrict__ dtg,
                                                  const float* __restrict__ acsg,
                                                  const unsigned short* __restrict__ prevs,
                                                  const float* __restrict__ Dp,
                                                  unsigned short* __restrict__ ybh) {
  int bid = blockIdx.x;
  int h = bid & 127, c = (bid >> 7) & 15, b = bid >> 11;
  int g = h & 7;
  int row0 = b * SEQ + c * CHK;
  __shared__ __align__(16) char smem[70144];
  unsigned short* Cst = (unsigned short*)smem;            // [128][40] Gm phase
  unsigned short* Bst = (unsigned short*)(smem + 10240);  // [128][40] Gm phase
  unsigned short* Mt = (unsigned short*)smem;             // [128][136]
  unsigned short* XT = (unsigned short*)(smem + 34816);   // [64][136]
  unsigned short* Sp = (unsigned short*)(smem + 52224);   // [64][136]
  float* Acs = (float*)(smem + 69632);                    // [128]
  int tid = threadIdx.x, lane = tid & 63, wv = tid >> 6;  // 8 waves
  int fo = (lane >> 4) * 8, il = lane & 15, rl = (lane >> 4) * 4;
  if (tid < 128) Acs[tid] = acsg[(((size_t)(b * NCH + c) * NH) + h) * CHK + tid];

  // phase1: Gm = C @ B^T ; save per-wave C fragments for phase5
  f32x4 gm[8];
#pragma unroll
  for (int i = 0; i < 8; ++i) gm[i] = (f32x4){0.f, 0.f, 0.f, 0.f};
  bf16x8 cf[4];
  int srow = tid >> 2, scol = (tid & 3) * 8;
#pragma unroll
  for (int kc = 0; kc < 4; ++kc) {
    __syncthreads();
    *(int4*)(Cst + srow * 40 + scol) =
        *(const int4*)(xbc + (size_t)(row0 + srow) * CONV_D + INTER_D + NG * NSD + g * NSD + kc * 32 + scol);
    *(int4*)(Bst + srow * 40 + scol) =
        *(const int4*)(xbc + (size_t)(row0 + srow) * CONV_D + INTER_D + g * NSD + kc * 32 + scol);
    __syncthreads();
    bf16x8 a = *(const bf16x8*)&Cst[(wv * 16 + il) * 40 + fo];
    cf[kc] = a;
#pragma unroll
    for (int ni = 0; ni < 8; ++ni) {
      bf16x8 bb = *(const bf16x8*)&Bst[(ni * 16 + il) * 40 + fo];
      gm[ni] = __builtin_amdgcn_mfma_f32_16x16x32_bf16(a, bb, gm[ni], 0, 0, 0);
    }
  }
  __syncthreads();
  // phase2: masked+decayed M -> Mt; stage XT = (hs*dt)^T; stage Sp = prevs (bf16 copy)
#pragma unroll
  for (int ni = 0; ni < 8; ++ni) {
    int s = ni * 16 + il;
#pragma unroll
    for (int r = 0; r < 4; ++r) {
      int ll = wv * 16 + rl + r;
      float v = (s <= ll) ? gm[ni][r] * __expf(Acs[ll] - Acs[s]) : 0.f;
      Mt[ll * 136 + s] = f2bf(v);
    }
  }
#pragma unroll
  for (int j = 0; j < 2; ++j) {
    int q = tid + j * 512;
    int ll = q >> 3, p0 = (q & 7) * 8;
    int row = row0 + ll;
    float dtv = dtg[(size_t)row * NH + h];
    int4 raw = *(const int4*)(xbc + (size_t)row * CONV_D + h * PD + p0);
    unsigned short* u = (unsigned short*)&raw;
#pragma unroll
    for (int e = 0; e < 8; ++e) XT[(p0 + e) * 136 + ll] = f2bf(bf2f(u[e]) * dtv);
  }
  size_t sbase = ((size_t)(b * NH + h) * NCH + c) * (PD * NSD);
#pragma unroll
  for (int j = 0; j < 2; ++j) {
    int q = tid + j * 512;
    int p = q >> 4, n0 = (q & 15) * 8;
    *(int4*)(Sp + p * 136 + n0) = *(const int4*)(prevs + sbase + p * NSD + n0);
  }
  __syncthreads();
  // phase3: Y_diag = M @ X ; fused phase5: Y_off = cf @ Sp^T (registers, no reload)
  f32x4 yd[4], yo[4];
#pragma unroll
  for (int i = 0; i < 4; ++i) {
    yd[i] = (f32x4){0.f, 0.f, 0.f, 0.f};
    yo[i] = (f32x4){0.f, 0.f, 0.f, 0.f};
  }
#pragma unroll
  for (int ks = 0; ks < 4; ++ks) {
    bf16x8 a = *(const bf16x8*)&Mt[(wv * 16 + il) * 136 + ks * 32 + fo];
#pragma unroll
    for (int pi = 0; pi < 4; ++pi) {
      bf16x8 bb = *(const bf16x8*)&XT[(pi * 16 + il) * 136 + ks * 32 + fo];
      bf16x8 sb = *(const bf16x8*)&Sp[(pi * 16 + il) * 136 + ks * 32 + fo];
      yd[pi] = __builtin_amdgcn_mfma_f32_16x16x32_bf16(a, bb, yd[pi], 0, 0, 0);
      yo[pi] = __builtin_amdgcn_mfma_f32_16x16x32_bf16(cf[ks], sb, yo[pi], 0, 0, 0);
    }
  }
  float dv = Dp[h];
#pragma unroll
  for (int pi = 0; pi < 4; ++pi) {
    int p = pi * 16 + il;
#pragma unroll
    for (int r = 0; r < 4; ++r) {
      int ll = wv * 16 + rl + r;
      int row = row0 + ll;
      float hsv = bf2f(xbc[(size_t)row * CONV_D + h * PD + p]);
      ybh[(size_t)row * INTER_D + h * PD + p] =
          f2bf(yd[pi][r] + yo[pi][r] * __expf(Acs[ll]) + dv * hsv);
    }
  }
}

// ---------------- F: gate silu, grouped RMSNorm (ushort4 vectorized) ----------------
__global__ __launch_bounds__(256) void fnorm_kernel(const unsigned short* __restrict__ ybh,
                                                    const unsigned short* __restrict__ proj,
                                                    const float* __restrict__ nw,
                                                    unsigned short* __restrict__ normed) {
  int row = blockIdx.x >> 3;
  int gg = blockIdx.x & 7;
  int t = threadIdx.x;
  int ch = gg * 1024 + t * 4;
  ushort4 yv = *(const ushort4*)(ybh + (size_t)row * INTER_D + ch);
  ushort4 gv = *(const ushort4*)(proj + (size_t)row * PROJ_D + ch);
  float v[4];
  float ss = 0.f;
  {
    const unsigned short* yp = (const unsigned short*)&yv;
    const unsigned short* gp = (const unsigned short*)&gv;
#pragma unroll
    for (int j = 0; j < 4; ++j) {
      float val = bf2f(yp[j]);
      float gt = bf2f(gp[j]);
      val *= gt / (1.f + __expf(-gt));
      v[j] = val;
      ss += val * val;
    }
  }
  // wave-level shuffle reduce (64 lanes), then 4-wave LDS combine
#pragma unroll
  for (int o = 1; o < 64; o <<= 1) ss += __shfl_xor(ss, o, 64);
  __shared__ float sred[4];
  if ((t & 63) == 0) sred[t >> 6] = ss;
  __syncthreads();
  float tot = sred[0] + sred[1] + sred[2] + sred[3];
  float rms = rsqrtf(tot / 1024.f + 1e-5f);
  float4 nwv = *(const float4*)(nw + ch);
  unsigned short o4[4];
  const float* nwp = (const float*)&nwv;
#pragma unroll
  for (int j = 0; j < 4; ++j) o4[j] = f2bf(v[j] * rms * nwp[j]);
  *(ushort4*)(normed + (size_t)row * INTER_D + ch) = *(ushort4*)o4;
}

extern "C" void kernel_launch(void* const* d_in, const int* in_sizes, int n_in,
                              void* d_out, int out_size, void* d_ws, size_t ws_size,
                              hipStream_t stream) {
  (void)in_sizes; (void)n_in; (void)out_size; (void)ws_size;
  const float* hs = (const float*)d_in[0];
  const float* w1 = (const float*)d_in[1];
  const float* cw = (const float*)d_in[2];
  const float* cb = (const float*)d_in[3];
  const float* dtb = (const float*)d_in[4];
  const float* alog = (const float*)d_in[5];
  const float* Dp = (const float*)d_in[6];
  const float* nw = (const float*)d_in[7];
  const float* w2 = (const float*)d_in[8];
  float* out = (float*)d_out;
  char* ws = (char*)d_ws;

  unsigned short* hsb = (unsigned short*)(ws);                 // 33,554,432
  unsigned short* w1b = (unsigned short*)(ws + 33554432);      // 153,092,096 (padded to 18688 rows)
  unsigned short* w2b = (unsigned short*)(ws + 186646528);     // 67,108,864
  unsigned short* proj = (unsigned short*)(ws + 253755392);    // 152,043,520
  unsigned short* xbc = (unsigned short*)(ws + 405798912);     // 83,886,080
  float* dtg = (float*)(ws + 489684992);                       // 2,097,152
  float* acsg = (float*)(ws + 491782144);                      // 2,097,152
  unsigned short* states16 = (unsigned short*)(ws + 493879296);// 67,108,864 (bf16)
  unsigned short* prevs = (unsigned short*)(ws + 560988160);   // 67,108,864 (bf16)
  unsigned short* ybh = (unsigned short*)(ws + 628097024);     // 67,108,864 (bf16)
  unsigned short* normed = (unsigned short*)(ws);              // reuses hsb region (dead)

  cvt_kernel<<<dim3(16384), dim3(256), 0, stream>>>(hs, hsb, (size_t)ROWS * HIDD);
  cvt_kernel<<<dim3(74240), dim3(256), 0, stream>>>(w1, w1b, (size_t)PROJ_D * HIDD);
  cvt_kernel<<<dim3(32768), dim3(256), 0, stream>>>(w2, w2b, (size_t)HIDD * INTER_D);

  gemm256<1><<<dim3(16 * 73), dim3(512), 0, stream>>>(hsb, w1b, proj, nullptr,
                                                      PROJ_D, HIDD, HIDD, 0);
  dts_kernel<<<dim3(32), dim3(128), 0, stream>>>(proj, dtb, alog, dtg, acsg);
  conv_kernel<<<dim3(5, 4096), dim3(256), 0, stream>>>(proj, cw, cb, xbc);
  e1b_kernel<<<dim3(4096), dim3(256), 0, stream>>>(xbc, dtg, acsg, states16);
  e2_kernel<<<dim3(1024), dim3(256), 0, stream>>>(acsg, states16, prevs);
  e13_kernel<<<dim3(4096), dim3(512), 0, stream>>>(xbc, dtg, acsg, prevs, Dp, ybh);
  fnorm_kernel<<<dim3(32768), dim3(256), 0, stream>>>(ybh, proj, nw, normed);
  gemm256<0><<<dim3(16 * 16), dim3(512), 0, stream>>>(normed, w2b, nullptr, out,
                                                      HIDD, INTER_D, INTER_D, 0);
}

// Round 14
// 1312.690 us; speedup vs baseline: 6.1460x; 1.0480x over previous
//
#include <hip/hip_runtime.h>

#define NH 128
#define PD 64
#define NSD 128
#define NG 8
#define CHK 128
#define HIDD 4096
#define INTER_D 8192
#define CONV_D 10240
#define PROJ_D 18560
#define SEQ 2048
#define ROWS 4096
#define NCH 16

typedef __attribute__((ext_vector_type(8))) short bf16x8;
typedef __attribute__((ext_vector_type(4))) float f32x4;

__device__ __forceinline__ unsigned short f2bf(float f) {
  unsigned int u = __float_as_uint(f);
  u += 0x7FFF + ((u >> 16) & 1);
  return (unsigned short)(u >> 16);
}
__device__ __forceinline__ float bf2f(unsigned short s) {
  return __uint_as_float(((unsigned int)s) << 16);
}

__device__ __forceinline__ void gld16(const unsigned short* g, unsigned short* l) {
  __builtin_amdgcn_global_load_lds(
      (__attribute__((address_space(1))) const void*)g,
      (__attribute__((address_space(3))) void*)l, 16, 0, 0);
}

#define BAR() __builtin_amdgcn_s_barrier()
#define SCHED() __builtin_amdgcn_sched_barrier(0)
#define VMCNT(n) asm volatile("s_waitcnt vmcnt(" #n ")" ::: "memory")

// swizzled LDS fragment read: slot is a [128][64] bf16 half-tile (16KB)
__device__ __forceinline__ bf16x8 ldsfrag(const unsigned short* slot, int row, int kslot) {
  int byte = row * 128 + (((kslot ^ (row & 7)) << 4));
  return *(const bf16x8*)((const char*)slot + byte);
}

// ---------------- merged f32 -> bf16 convert (hs, w1, w2 in one launch) ----------------
__global__ __launch_bounds__(256) void cvt_all_kernel(const float* __restrict__ hs,
                                                      const float* __restrict__ w1,
                                                      const float* __restrict__ w2,
                                                      unsigned short* __restrict__ hsb,
                                                      unsigned short* __restrict__ w1b,
                                                      unsigned short* __restrict__ w2b) {
  int bid = blockIdx.x;
  const float* in;
  unsigned short* out;
  size_t base;
  if (bid < 16384) {            // hs: 16,777,216 elems
    in = hs; out = hsb; base = (size_t)bid * 1024;
  } else if (bid < 16384 + 74240) {  // w1: 76,021,760 elems
    in = w1; out = w1b; base = (size_t)(bid - 16384) * 1024;
  } else {                      // w2: 33,554,432 elems
    in = w2; out = w2b; base = (size_t)(bid - 16384 - 74240) * 1024;
  }
  size_t i = base + (size_t)threadIdx.x * 4;
  float4 f = *(const float4*)(in + i);
  ushort4 o;
  o.x = f2bf(f.x); o.y = f2bf(f.y); o.z = f2bf(f.z); o.w = f2bf(f.w);
  *(ushort4*)(out + i) = o;
}

// ---------------- 256^2 4-phase GEMM, BK=64 (PROVEN; do not edit) ----------------
// 8 waves (2M x 4N). Stage always into the opposite buffer (race-free).
// 605-614us on GEMM1, reproduced rounds 3/5/7/8/11/12/13. All schedule variants
// regressed: burst(R4), t+2-prefetch(R6, raced), split-K(R8), BK=32(R9/R10).
template <int OUT_BF16>
__global__ __launch_bounds__(512, 2) void gemm256(const unsigned short* __restrict__ A,
                                                  const unsigned short* __restrict__ B,
                                                  unsigned short* __restrict__ outb,
                                                  float* __restrict__ outf,
                                                  int Nreal, int Ks, int Kl, int koff) {
  __shared__ unsigned short lds[8][8192];  // 8 half-slots x 16KB = 128KB
  int tid = threadIdx.x, l = tid & 63, w = tid >> 6;
  int wm = w >> 2, wn = w & 3;
  int il = l & 15, fog = l >> 4;
  int bid = blockIdx.x;
  int xcd = bid & 7, local = bid >> 3;
  int mt = xcd * 2 + (local & 1), nt = local >> 1;
  const unsigned short* Abase = A + (size_t)mt * 256 * Ks + koff;
  const unsigned short* Bbase = B + (size_t)nt * 256 * Ks + koff;
  int NT = Kl >> 6;

  f32x4 acc[2][2][4][2];
#pragma unroll
  for (int a = 0; a < 2; ++a)
#pragma unroll
    for (int b = 0; b < 2; ++b)
#pragma unroll
      for (int m = 0; m < 4; ++m)
#pragma unroll
        for (int n = 0; n < 2; ++n) acc[a][b][m][n] = (f32x4){0.f, 0.f, 0.f, 0.f};

  auto STG = [&](int tt, int ty) {
    int tc = tt < NT ? tt : NT - 1;
    const unsigned short* g = ((ty & 1) ? Bbase : Abase) + (size_t)((ty >> 1) * 128) * Ks + tc * 64;
    unsigned short* sp = (unsigned short*)lds[(tt & 1) * 4 + ty];
#pragma unroll
    for (int j = 0; j < 2; ++j) {
      int row = (j * 8 + w) * 8 + (l >> 3);
      int scol = ((l & 7) ^ (row & 7)) * 8;  // inverse-swizzled global source
      gld16(g + (size_t)row * Ks + scol, sp + (j * 8 + w) * 512);
    }
  };

#define LDA(SLOT)                                          \
  _Pragma("unroll") for (int mi = 0; mi < 4; ++mi)         \
  _Pragma("unroll") for (int kk = 0; kk < 2; ++kk)         \
      av[mi][kk] = ldsfrag(SLOT, wm * 64 + mi * 16 + il, kk * 4 + fog);
#define LDB(QN, SLOT)                                      \
  _Pragma("unroll") for (int ni = 0; ni < 2; ++ni)         \
  _Pragma("unroll") for (int kk = 0; kk < 2; ++kk)         \
      bv[QN][ni][kk] = ldsfrag(SLOT, wn * 32 + ni * 16 + il, kk * 4 + fog);
#define MFMA_PH(QM, QN)                                    \
  _Pragma("unroll") for (int mi = 0; mi < 4; ++mi)         \
  _Pragma("unroll") for (int ni = 0; ni < 2; ++ni)         \
  _Pragma("unroll") for (int kk = 0; kk < 2; ++kk)         \
      acc[QM][QN][mi][ni] = __builtin_amdgcn_mfma_f32_16x16x32_bf16( \
          av[mi][kk], bv[QN][ni][kk], acc[QM][QN][mi][ni], 0, 0, 0);

  // prologue: tile0 all 4 halves; leave A1 (ty2) in flight
  STG(0, 0); STG(0, 1); STG(0, 3); STG(0, 2);
  VMCNT(2);
  BAR(); SCHED();

  for (int t = 0; t < NT; ++t) {
    const unsigned short* sA0 = lds[(t & 1) * 4 + 0];
    const unsigned short* sB0 = lds[(t & 1) * 4 + 1];
    const unsigned short* sA1 = lds[(t & 1) * 4 + 2];
    const unsigned short* sB1 = lds[(t & 1) * 4 + 3];
    bf16x8 av[4][2], bv[2][2][2];
    // P1: read A0 + both B quadrants; stage A0,B0 of t+1
    LDA(sA0); LDB(0, sB0); LDB(1, sB1);
    STG(t + 1, 0); STG(t + 1, 1);
    BAR();
    __builtin_amdgcn_s_setprio(1);
    MFMA_PH(0, 0);
    __builtin_amdgcn_s_setprio(0);
    VMCNT(4);  // A1(t) landed (staged prev iter) -> safe for P3 reads
    BAR(); SCHED();
    // P2: pure MFMA; stage B1 of t+1
    STG(t + 1, 3);
    __builtin_amdgcn_s_setprio(1);
    MFMA_PH(0, 1);
    __builtin_amdgcn_s_setprio(0);
    BAR();
    // P3: read A1; stage A1 of t+1
    LDA(sA1);
    STG(t + 1, 2);
    BAR();
    __builtin_amdgcn_s_setprio(1);
    MFMA_PH(1, 0);
    __builtin_amdgcn_s_setprio(0);
    BAR();
    // P4: pure MFMA
    __builtin_amdgcn_s_setprio(1);
    MFMA_PH(1, 1);
    __builtin_amdgcn_s_setprio(0);
    VMCNT(2);  // A0,B0,B1(t+1) landed -> safe for next P1 reads
    BAR(); SCHED();
  }
  VMCNT(0);

  // epilogue: C write
  int rl = (l >> 4) * 4;
#pragma unroll
  for (int qm = 0; qm < 2; ++qm)
#pragma unroll
    for (int qn = 0; qn < 2; ++qn)
#pragma unroll
      for (int mi = 0; mi < 4; ++mi)
#pragma unroll
        for (int ni = 0; ni < 2; ++ni) {
          int grow = mt * 256 + qm * 128 + wm * 64 + mi * 16 + rl;
          int gcol = nt * 256 + qn * 128 + wn * 32 + ni * 16 + il;
          if (!OUT_BF16 || gcol < Nreal) {
#pragma unroll
            for (int r = 0; r < 4; ++r) {
              float v = acc[qm][qn][mi][ni][r];
              if (OUT_BF16)
                outb[(size_t)(grow + r) * Nreal + gcol] = f2bf(v);
              else
                outf[(size_t)(grow + r) * Nreal + gcol] = v;
            }
          }
        }
#undef LDA
#undef LDB
#undef MFMA_PH
}

// ---------------- dts phase A: softplus (massively parallel, coalesced) ----------------
__global__ __launch_bounds__(256) void dtsa_kernel(const unsigned short* __restrict__ proj,
                                                   const float* __restrict__ dt_bias,
                                                   float* __restrict__ dtg) {
  int idx = blockIdx.x * 256 + threadIdx.x;  // 0..524287
  int row = idx >> 7, h = idx & 127;
  float x = bf2f(proj[(size_t)row * PROJ_D + (PROJ_D - NH) + h]) + dt_bias[h];
  float d = (x > 20.f) ? x : log1pf(expf(x));
  dtg[(size_t)row * NH + h] = d;
}

// ---------------- dts phase B: A*dt cumsum over dtg (L2/L3-hot) ----------------
__global__ __launch_bounds__(128) void dtsb_kernel(const float* __restrict__ dtg,
                                                   const float* __restrict__ A_log,
                                                   float* __restrict__ acsg) {
  int bc = blockIdx.x;
  int h = threadIdx.x;
  int b = bc >> 4, c = bc & 15;
  float A = -__expf(A_log[h]);
  float cum = 0.f;
  int row0 = b * SEQ + c * CHK;
#pragma unroll 8
  for (int ll = 0; ll < CHK; ++ll) {
    cum += A * dtg[(size_t)(row0 + ll) * NH + h];
    acsg[(((size_t)bc * NH) + h) * CHK + ll] = cum;
  }
}

// ---------------- causal depthwise conv + bias + silu (8-wide vectorized) ----------------
__global__ __launch_bounds__(256) void conv_kernel(const unsigned short* __restrict__ proj,
                                                   const float* __restrict__ cw,
                                                   const float* __restrict__ cb,
                                                   unsigned short* __restrict__ xbc) {
  int ch0 = (blockIdx.x * 256 + threadIdx.x) * 8;  // grid.x = 5 -> 10240 channels
  int row = blockIdx.y;
  int b = row >> 11, ll = row & 2047;
  float4 cwv[8];
#pragma unroll
  for (int e = 0; e < 8; ++e) cwv[e] = *(const float4*)(cw + (ch0 + e) * 4);
  float acc[8];
#pragma unroll
  for (int e = 0; e < 8; ++e) acc[e] = cb[ch0 + e];
#pragma unroll
  for (int k = 0; k < 4; ++k) {
    int l2 = ll - 3 + k;
    if (l2 >= 0) {
      bf16x8 v = *(const bf16x8*)(proj + (size_t)(b * SEQ + l2) * PROJ_D + INTER_D + ch0);
#pragma unroll
      for (int e = 0; e < 8; ++e)
        acc[e] += bf2f(((unsigned short*)&v)[e]) * ((const float*)&cwv[e])[k];
    }
  }
  unsigned short o[8];
#pragma unroll
  for (int e = 0; e < 8; ++e) {
    float s = acc[e] / (1.f + __expf(-acc[e]));
    o[e] = f2bf(s);
  }
  *(int4*)(xbc + (size_t)row * CONV_D + ch0) = *(int4*)o;
}

// ---------------- E1b: states = X^T @ B_decay (bf16 out) ----------------
__global__ __launch_bounds__(256) void e1b_kernel(const unsigned short* __restrict__ xbc,
                                                  const float* __restrict__ dtg,
                                                  const float* __restrict__ acsg,
                                                  unsigned short* __restrict__ states16) {
  int bid = blockIdx.x;
  int h = bid & 127, c = (bid >> 7) & 15, b = bid >> 11;
  int g = h & 7;
  int row0 = b * SEQ + c * CHK;
  __shared__ __align__(16) char smem[52736];
  unsigned short* XT = (unsigned short*)smem;
  unsigned short* BdT = (unsigned short*)(smem + 17408);
  float* Acs = (float*)(smem + 52224);
  int tid = threadIdx.x, lane = tid & 63, wv = tid >> 6;
  int fo = (lane >> 4) * 8, il = lane & 15, rl = (lane >> 4) * 4;
  if (tid < 128) Acs[tid] = acsg[(((size_t)(b * NCH + c) * NH) + h) * CHK + tid];
  __syncthreads();
#pragma unroll
  for (int j = 0; j < 4; ++j) {
    int q = tid + j * 256;
    int ll = q >> 3, p0 = (q & 7) * 8;
    int row = row0 + ll;
    float dtv = dtg[(size_t)row * NH + h];
    int4 raw = *(const int4*)(xbc + (size_t)row * CONV_D + h * PD + p0);
    unsigned short* u = (unsigned short*)&raw;
#pragma unroll
    for (int e = 0; e < 8; ++e) XT[(p0 + e) * 136 + ll] = f2bf(bf2f(u[e]) * dtv);
  }
#pragma unroll
  for (int j = 0; j < 8; ++j) {
    int q = tid + j * 256;
    int ll = q >> 4, n0 = (q & 15) * 8;
    float dec = __expf(Acs[CHK - 1] - Acs[ll]);
    int4 raw = *(const int4*)(xbc + (size_t)(row0 + ll) * CONV_D + INTER_D + g * NSD + n0);
    unsigned short* u = (unsigned short*)&raw;
#pragma unroll
    for (int e = 0; e < 8; ++e) BdT[(n0 + e) * 136 + ll] = f2bf(bf2f(u[e]) * dec);
  }
  __syncthreads();
  f32x4 st[8];
#pragma unroll
  for (int i = 0; i < 8; ++i) st[i] = (f32x4){0.f, 0.f, 0.f, 0.f};
#pragma unroll
  for (int ks = 0; ks < 4; ++ks) {
    bf16x8 a = *(const bf16x8*)&XT[(wv * 16 + il) * 136 + ks * 32 + fo];
#pragma unroll
    for (int ni = 0; ni < 8; ++ni) {
      bf16x8 bb = *(const bf16x8*)&BdT[(ni * 16 + il) * 136 + ks * 32 + fo];
      st[ni] = __builtin_amdgcn_mfma_f32_16x16x32_bf16(a, bb, st[ni], 0, 0, 0);
    }
  }
  size_t base = ((size_t)(b * NH + h) * NCH + c) * (PD * NSD);
#pragma unroll
  for (int ni = 0; ni < 8; ++ni) {
    int n = ni * 16 + il;
#pragma unroll
    for (int r = 0; r < 4; ++r) {
      int p = wv * 16 + rl + r;
      states16[base + p * NSD + n] = f2bf(st[ni][r]);
    }
  }
}

// ---------------- E2: chunk-state scan (bf16x8 per thread, f32 accum) ----------------
__global__ __launch_bounds__(256) void e2_kernel(const float* __restrict__ acsg,
                                                 const unsigned short* __restrict__ states16,
                                                 unsigned short* __restrict__ prevs) {
  int bid = blockIdx.x;          // (b*128+h)*4 + pg
  int bh = bid >> 2, pg = bid & 3;
  int b = bh >> 7;
  int t = threadIdx.x;
  float S[8];
#pragma unroll
  for (int j = 0; j < 8; ++j) S[j] = 0.f;
  for (int c = 0; c < NCH; ++c) {
    float alast = acsg[(((size_t)((b * NCH + c) * NH) + (bh & 127))) * CHK + (CHK - 1)];
    float dec = __expf(alast);
    size_t base = ((size_t)bh * NCH + c) * (PD * NSD) + (size_t)pg * 2048 + (size_t)t * 8;
    bf16x8 v = *(const bf16x8*)(states16 + base);
    unsigned short o[8];
#pragma unroll
    for (int j = 0; j < 8; ++j) {
      o[j] = f2bf(S[j]);
      S[j] = S[j] * dec + bf2f(((unsigned short*)&v)[j]);
    }
    *(bf16x8*)(prevs + base) = *(bf16x8*)o;
  }
}

// ---------------- E13: fused Y_diag + Y_off + D_res -> yb (bf16 out) ----------------
// phase1's per-wave C fragments saved in registers (cf[kc]) and reused as phase5's
// A-operand (identical coverage) -> no phase4 C reload, 2 fewer barriers.
__global__ __launch_bounds__(512) void e13_kernel(const unsigned short* __restrict__ xbc,
                                                  const float* __restrict__ dtg,
                                                  const float* __restrict__ acsg,
                                                  const unsigned short* __restrict__ prevs,
                                                  const float* __restrict__ Dp,
                                                  unsigned short* __restrict__ ybh) {
  int bid = blockIdx.x;
  int h = bid & 127, c = (bid >> 7) & 15, b = bid >> 11;
  int g = h & 7;
  int row0 = b * SEQ + c * CHK;
  __shared__ __align__(16) char smem[70144];
  unsigned short* Cst = (unsigned short*)smem;            // [128][40] Gm phase
  unsigned short* Bst = (unsigned short*)(smem + 10240);  // [128][40] Gm phase
  unsigned short* Mt = (unsigned short*)smem;             // [128][136]
  unsigned short* XT = (unsigned short*)(smem + 34816);   // [64][136]
  unsigned short* Sp = (unsigned short*)(smem + 52224);   // [64][136]
  float* Acs = (float*)(smem + 69632);                    // [128]
  int tid = threadIdx.x, lane = tid & 63, wv = tid >> 6;  // 8 waves
  int fo = (lane >> 4) * 8, il = lane & 15, rl = (lane >> 4) * 4;
  if (tid < 128) Acs[tid] = acsg[(((size_t)(b * NCH + c) * NH) + h) * CHK + tid];

  // phase1: Gm = C @ B^T ; save per-wave C fragments for phase5
  f32x4 gm[8];
#pragma unroll
  for (int i = 0; i < 8; ++i) gm[i] = (f32x4){0.f, 0.f, 0.f, 0.f};
  bf16x8 cf[4];
  int srow = tid >> 2, scol = (tid & 3) * 8;
#pragma unroll
  for (int kc = 0; kc < 4; ++kc) {
    __syncthreads();
    *(int4*)(Cst + srow * 40 + scol) =
        *(const int4*)(xbc + (size_t)(row0 + srow) * CONV_D + INTER_D + NG * NSD + g * NSD + kc * 32 + scol);
    *(int4*)(Bst + srow * 40 + scol) =
        *(const int4*)(xbc + (size_t)(row0 + srow) * CONV_D + INTER_D + g * NSD + kc * 32 + scol);
    __syncthreads();
    bf16x8 a = *(const bf16x8*)&Cst[(wv * 16 + il) * 40 + fo];
    cf[kc] = a;
#pragma unroll
    for (int ni = 0; ni < 8; ++ni) {
      bf16x8 bb = *(const bf16x8*)&Bst[(ni * 16 + il) * 40 + fo];
      gm[ni] = __builtin_amdgcn_mfma_f32_16x16x32_bf16(a, bb, gm[ni], 0, 0, 0);
    }
  }
  __syncthreads();
  // phase2: masked+decayed M -> Mt; stage XT = (hs*dt)^T; stage Sp = prevs (bf16 copy)
#pragma unroll
  for (int ni = 0; ni < 8; ++ni) {
    int s = ni * 16 + il;
#pragma unroll
    for (int r = 0; r < 4; ++r) {
      int ll = wv * 16 + rl + r;
      float v = (s <= ll) ? gm[ni][r] * __expf(Acs[ll] - Acs[s]) : 0.f;
      Mt[ll * 136 + s] = f2bf(v);
    }
  }
#pragma unroll
  for (int j = 0; j < 2; ++j) {
    int q = tid + j * 512;
    int ll = q >> 3, p0 = (q & 7) * 8;
    int row = row0 + ll;
    float dtv = dtg[(size_t)row * NH + h];
    int4 raw = *(const int4*)(xbc + (size_t)row * CONV_D + h * PD + p0);
    unsigned short* u = (unsigned short*)&raw;
#pragma unroll
    for (int e = 0; e < 8; ++e) XT[(p0 + e) * 136 + ll] = f2bf(bf2f(u[e]) * dtv);
  }
  size_t sbase = ((size_t)(b * NH + h) * NCH + c) * (PD * NSD);
#pragma unroll
  for (int j = 0; j < 2; ++j) {
    int q = tid + j * 512;
    int p = q >> 4, n0 = (q & 15) * 8;
    *(int4*)(Sp + p * 136 + n0) = *(const int4*)(prevs + sbase + p * NSD + n0);
  }
  __syncthreads();
  // phase3: Y_diag = M @ X ; fused phase5: Y_off = cf @ Sp^T (registers, no reload)
  f32x4 yd[4], yo[4];
#pragma unroll
  for (int i = 0; i < 4; ++i) {
    yd[i] = (f32x4){0.f, 0.f, 0.f, 0.f};
    yo[i] = (f32x4){0.f, 0.f, 0.f, 0.f};
  }
#pragma unroll
  for (int ks = 0; ks < 4; ++ks) {
    bf16x8 a = *(const bf16x8*)&Mt[(wv * 16 + il) * 136 + ks * 32 + fo];
#pragma unroll
    for (int pi = 0; pi < 4; ++pi) {
      bf16x8 bb = *(const bf16x8*)&XT[(pi * 16 + il) * 136 + ks * 32 + fo];
      bf16x8 sb = *(const bf16x8*)&Sp[(pi * 16 + il) * 136 + ks * 32 + fo];
      yd[pi] = __builtin_amdgcn_mfma_f32_16x16x32_bf16(a, bb, yd[pi], 0, 0, 0);
      yo[pi] = __builtin_amdgcn_mfma_f32_16x16x32_bf16(cf[ks], sb, yo[pi], 0, 0, 0);
    }
  }
  float dv = Dp[h];
#pragma unroll
  for (int pi = 0; pi < 4; ++pi) {
    int p = pi * 16 + il;
#pragma unroll
    for (int r = 0; r < 4; ++r) {
      int ll = wv * 16 + rl + r;
      int row = row0 + ll;
      float hsv = bf2f(xbc[(size_t)row * CONV_D + h * PD + p]);
      ybh[(size_t)row * INTER_D + h * PD + p] =
          f2bf(yd[pi][r] + yo[pi][r] * __expf(Acs[ll]) + dv * hsv);
    }
  }
}

// ---------------- F: gate silu, grouped RMSNorm (wave-per-group, shuffle-only) ----------------
__global__ __launch_bounds__(256) void fnorm_kernel(const unsigned short* __restrict__ ybh,
                                                    const unsigned short* __restrict__ proj,
                                                    const float* __restrict__ nw,
                                                    unsigned short* __restrict__ normed) {
  int gid = blockIdx.x * 4 + (threadIdx.x >> 6);  // group index 0..32767
  int lane = threadIdx.x & 63;
  int row = gid >> 3, gg = gid & 7;
  int ch = gg * 1024 + lane * 16;
  bf16x8 y0 = *(const bf16x8*)(ybh + (size_t)row * INTER_D + ch);
  bf16x8 y1 = *(const bf16x8*)(ybh + (size_t)row * INTER_D + ch + 8);
  bf16x8 g0 = *(const bf16x8*)(proj + (size_t)row * PROJ_D + ch);
  bf16x8 g1 = *(const bf16x8*)(proj + (size_t)row * PROJ_D + ch + 8);
  float v[16];
  float ss = 0.f;
#pragma unroll
  for (int j = 0; j < 8; ++j) {
    float val = bf2f(((unsigned short*)&y0)[j]);
    float gt = bf2f(((unsigned short*)&g0)[j]);
    val *= gt / (1.f + __expf(-gt));
    v[j] = val; ss += val * val;
  }
#pragma unroll
  for (int j = 0; j < 8; ++j) {
    float val = bf2f(((unsigned short*)&y1)[j]);
    float gt = bf2f(((unsigned short*)&g1)[j]);
    val *= gt / (1.f + __expf(-gt));
    v[8 + j] = val; ss += val * val;
  }
#pragma unroll
  for (int o = 1; o < 64; o <<= 1) ss += __shfl_xor(ss, o, 64);
  float rms = rsqrtf(ss / 1024.f + 1e-5f);
  unsigned short o16[16];
#pragma unroll
  for (int q = 0; q < 4; ++q) {
    float4 nwv = *(const float4*)(nw + ch + q * 4);
    const float* nwp = (const float*)&nwv;
#pragma unroll
    for (int j = 0; j < 4; ++j) o16[q * 4 + j] = f2bf(v[q * 4 + j] * rms * nwp[j]);
  }
  *(int4*)(normed + (size_t)row * INTER_D + ch) = *(int4*)o16;
  *(int4*)(normed + (size_t)row * INTER_D + ch + 8) = *(int4*)(o16 + 8);
}

extern "C" void kernel_launch(void* const* d_in, const int* in_sizes, int n_in,
                              void* d_out, int out_size, void* d_ws, size_t ws_size,
                              hipStream_t stream) {
  (void)in_sizes; (void)n_in; (void)out_size; (void)ws_size;
  const float* hs = (const float*)d_in[0];
  const float* w1 = (const float*)d_in[1];
  const float* cw = (const float*)d_in[2];
  const float* cb = (const float*)d_in[3];
  const float* dtb = (const float*)d_in[4];
  const float* alog = (const float*)d_in[5];
  const float* Dp = (const float*)d_in[6];
  const float* nw = (const float*)d_in[7];
  const float* w2 = (const float*)d_in[8];
  float* out = (float*)d_out;
  char* ws = (char*)d_ws;

  unsigned short* hsb = (unsigned short*)(ws);                 // 33,554,432
  unsigned short* w1b = (unsigned short*)(ws + 33554432);      // 153,092,096 (padded to 18688 rows)
  unsigned short* w2b = (unsigned short*)(ws + 186646528);     // 67,108,864
  unsigned short* proj = (unsigned short*)(ws + 253755392);    // 152,043,520
  unsigned short* xbc = (unsigned short*)(ws + 405798912);     // 83,886,080
  float* dtg = (float*)(ws + 489684992);                       // 2,097,152
  float* acsg = (float*)(ws + 491782144);                      // 2,097,152
  unsigned short* states16 = (unsigned short*)(ws + 493879296);// 67,108,864 (bf16)
  unsigned short* prevs = (unsigned short*)(ws + 560988160);   // 67,108,864 (bf16)
  unsigned short* ybh = (unsigned short*)(ws + 628097024);     // 67,108,864 (bf16)
  unsigned short* normed = (unsigned short*)(ws);              // reuses hsb region (dead)

  cvt_all_kernel<<<dim3(123392), dim3(256), 0, stream>>>(hs, w1, w2, hsb, w1b, w2b);

  gemm256<1><<<dim3(16 * 73), dim3(512), 0, stream>>>(hsb, w1b, proj, nullptr,
                                                      PROJ_D, HIDD, HIDD, 0);
  dtsa_kernel<<<dim3(2048), dim3(256), 0, stream>>>(proj, dtb, dtg);
  dtsb_kernel<<<dim3(32), dim3(128), 0, stream>>>(dtg, alog, acsg);
  conv_kernel<<<dim3(5, 4096), dim3(256), 0, stream>>>(proj, cw, cb, xbc);
  e1b_kernel<<<dim3(4096), dim3(256), 0, stream>>>(xbc, dtg, acsg, states16);
  e2_kernel<<<dim3(1024), dim3(256), 0, stream>>>(acsg, states16, prevs);
  e13_kernel<<<dim3(4096), dim3(512), 0, stream>>>(xbc, dtg, acsg, prevs, Dp, ybh);
  fnorm_kernel<<<dim3(8192), dim3(256), 0, stream>>>(ybh, proj, nw, normed);
  gemm256<0><<<dim3(16 * 16), dim3(512), 0, stream>>>(normed, w2b, nullptr, out,
                                                      HIDD, INTER_D, INTER_D, 0);
}

// Round 15
// 1291.981 us; speedup vs baseline: 6.2445x; 1.0160x over previous
//
#include <hip/hip_runtime.h>

#define NH 128
#define PD 64
#define NSD 128
#define NG 8
#define CHK 128
#define HIDD 4096
#define INTER_D 8192
#define CONV_D 10240
#define PROJ_D 18560
#define SEQ 2048
#define ROWS 4096
#define NCH 16

typedef __attribute__((ext_vector_type(8))) short bf16x8;
typedef __attribute__((ext_vector_type(4))) float f32x4;

__device__ __forceinline__ unsigned short f2bf(float f) {
  unsigned int u = __float_as_uint(f);
  u += 0x7FFF + ((u >> 16) & 1);
  return (unsigned short)(u >> 16);
}
__device__ __forceinline__ float bf2f(unsigned short s) {
  return __uint_as_float(((unsigned int)s) << 16);
}

__device__ __forceinline__ void gld16(const unsigned short* g, unsigned short* l) {
  __builtin_amdgcn_global_load_lds(
      (__attribute__((address_space(1))) const void*)g,
      (__attribute__((address_space(3))) void*)l, 16, 0, 0);
}

#define SCHED() __builtin_amdgcn_sched_barrier(0)
#define VMCNT(n) asm volatile("s_waitcnt vmcnt(" #n ")" ::: "memory")
#define LGKM(n) asm volatile("s_waitcnt lgkmcnt(" #n ")" ::: "memory")
// FENCED barrier: raw s_barrier is NOT a compiler memory fence (R6 raced on
// hoisted global_load_lds). The asm memory clobbers pin all memory ops.
#define BARF()                              \
  do {                                      \
    asm volatile("" ::: "memory");          \
    __builtin_amdgcn_s_barrier();           \
    asm volatile("" ::: "memory");          \
  } while (0)

// swizzled LDS fragment read: slot is a [128][64] bf16 half-tile (16KB)
__device__ __forceinline__ bf16x8 ldsfrag(const unsigned short* slot, int row, int kslot) {
  int byte = row * 128 + (((kslot ^ (row & 7)) << 4));
  return *(const bf16x8*)((const char*)slot + byte);
}

// ---------------- merged f32 -> bf16 convert (hs, w1, w2 in one launch) ----------------
__global__ __launch_bounds__(256) void cvt_all_kernel(const float* __restrict__ hs,
                                                      const float* __restrict__ w1,
                                                      const float* __restrict__ w2,
                                                      unsigned short* __restrict__ hsb,
                                                      unsigned short* __restrict__ w1b,
                                                      unsigned short* __restrict__ w2b) {
  int bid = blockIdx.x;
  const float* in;
  unsigned short* out;
  size_t base;
  if (bid < 16384) {            // hs: 16,777,216 elems
    in = hs; out = hsb; base = (size_t)bid * 1024;
  } else if (bid < 16384 + 74240) {  // w1: 76,021,760 elems
    in = w1; out = w1b; base = (size_t)(bid - 16384) * 1024;
  } else {                      // w2: 33,554,432 elems
    in = w2; out = w2b; base = (size_t)(bid - 16384 - 74240) * 1024;
  }
  size_t i = base + (size_t)threadIdx.x * 4;
  float4 f = *(const float4*)(in + i);
  ushort4 o;
  o.x = f2bf(f.x); o.y = f2bf(f.y); o.z = f2bf(f.z); o.w = f2bf(f.w);
  *(ushort4*)(out + i) = o;
}

// ---------------- 256^2 8-phase GEMM, BK=64 (m201 schedule, fenced barriers) ----------
// 8 waves (2M x 4N). Per tile: P1{read A0,B0,B1; stage A1(t+1)->opp}, P2{pure MFMA;
// stage A0(t+2)->same}, P3{read A1; stage B0(t+2)}, P4{pure MFMA; stage B1(t+2);
// VMCNT(6)}. Same-buffer stages are >=2 fenced barriers after the slot's last read.
// One counted vmcnt per K-tile; loads have 3-6 phases of latency cover.
template <int OUT_BF16>
__global__ __launch_bounds__(512, 2) void gemm256(const unsigned short* __restrict__ A,
                                                  const unsigned short* __restrict__ B,
                                                  unsigned short* __restrict__ outb,
                                                  float* __restrict__ outf,
                                                  int Nreal, int Ks, int Kl, int koff) {
  __shared__ unsigned short lds[8][8192];  // 8 half-slots x 16KB = 128KB
  int tid = threadIdx.x, l = tid & 63, w = tid >> 6;
  int wm = w >> 2, wn = w & 3;
  int il = l & 15, fog = l >> 4;
  int bid = blockIdx.x;
  int xcd = bid & 7, local = bid >> 3;
  int mt = xcd * 2 + (local & 1), nt = local >> 1;
  const unsigned short* Abase = A + (size_t)mt * 256 * Ks + koff;
  const unsigned short* Bbase = B + (size_t)nt * 256 * Ks + koff;
  int NT = Kl >> 6;  // always even (64 or 128)

  f32x4 acc[2][2][4][2];
#pragma unroll
  for (int a = 0; a < 2; ++a)
#pragma unroll
    for (int b = 0; b < 2; ++b)
#pragma unroll
      for (int m = 0; m < 4; ++m)
#pragma unroll
        for (int n = 0; n < 2; ++n) acc[a][b][m][n] = (f32x4){0.f, 0.f, 0.f, 0.f};

  // stage half-tile ty (0:A0 1:B0 2:A1 3:B1) of k-tile tt (clamped; uniform vmcnt).
  // Each wave issues 2 gld16 -> vmcnt +2 per STG.
  auto STG = [&](int tt, int ty) {
    int tc = tt < NT ? tt : NT - 1;
    const unsigned short* g = ((ty & 1) ? Bbase : Abase) + (size_t)((ty >> 1) * 128) * Ks + tc * 64;
    unsigned short* sp = (unsigned short*)lds[(tt & 1) * 4 + ty];
#pragma unroll
    for (int j = 0; j < 2; ++j) {
      int row = (j * 8 + w) * 8 + (l >> 3);
      int scol = ((l & 7) ^ (row & 7)) * 8;  // inverse-swizzled global source
      gld16(g + (size_t)row * Ks + scol, sp + (j * 8 + w) * 512);
    }
  };

#define LDA(SLOT)                                          \
  _Pragma("unroll") for (int mi = 0; mi < 4; ++mi)         \
  _Pragma("unroll") for (int kk = 0; kk < 2; ++kk)         \
      av[mi][kk] = ldsfrag(SLOT, wm * 64 + mi * 16 + il, kk * 4 + fog);
#define LDBQ(DST, SLOT)                                    \
  _Pragma("unroll") for (int ni = 0; ni < 2; ++ni)         \
  _Pragma("unroll") for (int kk = 0; kk < 2; ++kk)         \
      DST[ni][kk] = ldsfrag(SLOT, wn * 32 + ni * 16 + il, kk * 4 + fog);
#define MFMA_PH(QM, QN, BV)                                \
  _Pragma("unroll") for (int mi = 0; mi < 4; ++mi)         \
  _Pragma("unroll") for (int ni = 0; ni < 2; ++ni)         \
  _Pragma("unroll") for (int kk = 0; kk < 2; ++kk)         \
      acc[QM][QN][mi][ni] = __builtin_amdgcn_mfma_f32_16x16x32_bf16( \
          av[mi][kk], BV[ni][kk], acc[QM][QN][mi][ni], 0, 0, 0);

#define PH_TILE(BI, T)                                                       \
  {                                                                          \
    const unsigned short* sA0 = lds[(BI) * 4 + 0];                           \
    const unsigned short* sB0 = lds[(BI) * 4 + 1];                           \
    const unsigned short* sA1 = lds[(BI) * 4 + 2];                           \
    const unsigned short* sB1 = lds[(BI) * 4 + 3];                           \
    bf16x8 av[4][2], bv0[2][2], bv1[2][2];                                   \
    /* P1: read A0 + both B quadrants (16); stage A1(t+1) -> opposite buf */ \
    LDA(sA0); LDBQ(bv0, sB0); LDBQ(bv1, sB1);                                \
    STG((T) + 1, 2);                                                         \
    LGKM(8);                                                                 \
    BARF();                                                                  \
    LGKM(0); SCHED();                                                        \
    __builtin_amdgcn_s_setprio(1); MFMA_PH(0, 0, bv0);                       \
    __builtin_amdgcn_s_setprio(0);                                           \
    BARF();                                                                  \
    /* P2: pure MFMA; stage A0(t+2) -> same buf (A0 last read P1) */         \
    STG((T) + 2, 0);                                                         \
    BARF();                                                                  \
    SCHED();                                                                 \
    __builtin_amdgcn_s_setprio(1); MFMA_PH(0, 1, bv1);                       \
    __builtin_amdgcn_s_setprio(0);                                           \
    BARF();                                                                  \
    /* P3: read A1 (8); stage B0(t+2) -> same buf (B0 last read P1) */       \
    LDA(sA1);                                                                \
    STG((T) + 2, 1);                                                         \
    BARF();                                                                  \
    LGKM(0); SCHED();                                                        \
    __builtin_amdgcn_s_setprio(1); MFMA_PH(1, 0, bv0);                       \
    __builtin_amdgcn_s_setprio(0);                                           \
    BARF();                                                                  \
    /* P4: pure MFMA; stage B1(t+2); single counted drain for this tile */   \
    STG((T) + 2, 3);                                                         \
    BARF();                                                                  \
    SCHED();                                                                 \
    __builtin_amdgcn_s_setprio(1); MFMA_PH(1, 1, bv1);                       \
    __builtin_amdgcn_s_setprio(0);                                           \
    VMCNT(6);                                                                \
    BARF();                                                                  \
  }

  // prologue: A0,B0,B1,A1 of t0 + A0,B0,B1 of t1 (14 loads); drain to 6 in flight
  STG(0, 0); STG(0, 1); STG(0, 3); STG(0, 2);
  STG(1, 0); STG(1, 1); STG(1, 3);
  VMCNT(6);
  BARF(); SCHED();

  for (int t = 0; t < NT; t += 2) {
    PH_TILE(0, t);
    PH_TILE(1, t + 1);
  }
  VMCNT(0);  // drain clamped tail stages before LDS handoff

  // epilogue: C write
  int rl = (l >> 4) * 4;
#pragma unroll
  for (int qm = 0; qm < 2; ++qm)
#pragma unroll
    for (int qn = 0; qn < 2; ++qn)
#pragma unroll
      for (int mi = 0; mi < 4; ++mi)
#pragma unroll
        for (int ni = 0; ni < 2; ++ni) {
          int grow = mt * 256 + qm * 128 + wm * 64 + mi * 16 + rl;
          int gcol = nt * 256 + qn * 128 + wn * 32 + ni * 16 + il;
          if (!OUT_BF16 || gcol < Nreal) {
#pragma unroll
            for (int r = 0; r < 4; ++r) {
              float v = acc[qm][qn][mi][ni][r];
              if (OUT_BF16)
                outb[(size_t)(grow + r) * Nreal + gcol] = f2bf(v);
              else
                outf[(size_t)(grow + r) * Nreal + gcol] = v;
            }
          }
        }
#undef LDA
#undef LDBQ
#undef MFMA_PH
#undef PH_TILE
}

// ---------------- dts phase A: softplus (massively parallel, coalesced) ----------------
__global__ __launch_bounds__(256) void dtsa_kernel(const unsigned short* __restrict__ proj,
                                                   const float* __restrict__ dt_bias,
                                                   float* __restrict__ dtg) {
  int idx = blockIdx.x * 256 + threadIdx.x;  // 0..524287
  int row = idx >> 7, h = idx & 127;
  float x = bf2f(proj[(size_t)row * PROJ_D + (PROJ_D - NH) + h]) + dt_bias[h];
  float d = (x > 20.f) ? x : log1pf(expf(x));
  dtg[(size_t)row * NH + h] = d;
}

// ---------------- dts phase B: A*dt cumsum over dtg (L2/L3-hot) ----------------
__global__ __launch_bounds__(128) void dtsb_kernel(const float* __restrict__ dtg,
                                                   const float* __restrict__ A_log,
                                                   float* __restrict__ acsg) {
  int bc = blockIdx.x;
  int h = threadIdx.x;
  int b = bc >> 4, c = bc & 15;
  float A = -__expf(A_log[h]);
  float cum = 0.f;
  int row0 = b * SEQ + c * CHK;
#pragma unroll 8
  for (int ll = 0; ll < CHK; ++ll) {
    cum += A * dtg[(size_t)(row0 + ll) * NH + h];
    acsg[(((size_t)bc * NH) + h) * CHK + ll] = cum;
  }
}

// ---------------- causal depthwise conv + bias + silu (8-wide vectorized) ----------------
__global__ __launch_bounds__(256) void conv_kernel(const unsigned short* __restrict__ proj,
                                                   const float* __restrict__ cw,
                                                   const float* __restrict__ cb,
                                                   unsigned short* __restrict__ xbc) {
  int ch0 = (blockIdx.x * 256 + threadIdx.x) * 8;  // grid.x = 5 -> 10240 channels
  int row = blockIdx.y;
  int b = row >> 11, ll = row & 2047;
  float4 cwv[8];
#pragma unroll
  for (int e = 0; e < 8; ++e) cwv[e] = *(const float4*)(cw + (ch0 + e) * 4);
  float acc[8];
#pragma unroll
  for (int e = 0; e < 8; ++e) acc[e] = cb[ch0 + e];
#pragma unroll
  for (int k = 0; k < 4; ++k) {
    int l2 = ll - 3 + k;
    if (l2 >= 0) {
      bf16x8 v = *(const bf16x8*)(proj + (size_t)(b * SEQ + l2) * PROJ_D + INTER_D + ch0);
#pragma unroll
      for (int e = 0; e < 8; ++e)
        acc[e] += bf2f(((unsigned short*)&v)[e]) * ((const float*)&cwv[e])[k];
    }
  }
  unsigned short o[8];
#pragma unroll
  for (int e = 0; e < 8; ++e) {
    float s = acc[e] / (1.f + __expf(-acc[e]));
    o[e] = f2bf(s);
  }
  *(int4*)(xbc + (size_t)row * CONV_D + ch0) = *(int4*)o;
}

// ---------------- E1b: states = X^T @ B_decay (bf16 out) ----------------
__global__ __launch_bounds__(256) void e1b_kernel(const unsigned short* __restrict__ xbc,
                                                  const float* __restrict__ dtg,
                                                  const float* __restrict__ acsg,
                                                  unsigned short* __restrict__ states16) {
  int bid = blockIdx.x;
  int h = bid & 127, c = (bid >> 7) & 15, b = bid >> 11;
  int g = h & 7;
  int row0 = b * SEQ + c * CHK;
  __shared__ __align__(16) char smem[52736];
  unsigned short* XT = (unsigned short*)smem;
  unsigned short* BdT = (unsigned short*)(smem + 17408);
  float* Acs = (float*)(smem + 52224);
  int tid = threadIdx.x, lane = tid & 63, wv = tid >> 6;
  int fo = (lane >> 4) * 8, il = lane & 15, rl = (lane >> 4) * 4;
  if (tid < 128) Acs[tid] = acsg[(((size_t)(b * NCH + c) * NH) + h) * CHK + tid];
  __syncthreads();
#pragma unroll
  for (int j = 0; j < 4; ++j) {
    int q = tid + j * 256;
    int ll = q >> 3, p0 = (q & 7) * 8;
    int row = row0 + ll;
    float dtv = dtg[(size_t)row * NH + h];
    int4 raw = *(const int4*)(xbc + (size_t)row * CONV_D + h * PD + p0);
    unsigned short* u = (unsigned short*)&raw;
#pragma unroll
    for (int e = 0; e < 8; ++e) XT[(p0 + e) * 136 + ll] = f2bf(bf2f(u[e]) * dtv);
  }
#pragma unroll
  for (int j = 0; j < 8; ++j) {
    int q = tid + j * 256;
    int ll = q >> 4, n0 = (q & 15) * 8;
    float dec = __expf(Acs[CHK - 1] - Acs[ll]);
    int4 raw = *(const int4*)(xbc + (size_t)(row0 + ll) * CONV_D + INTER_D + g * NSD + n0);
    unsigned short* u = (unsigned short*)&raw;
#pragma unroll
    for (int e = 0; e < 8; ++e) BdT[(n0 + e) * 136 + ll] = f2bf(bf2f(u[e]) * dec);
  }
  __syncthreads();
  f32x4 st[8];
#pragma unroll
  for (int i = 0; i < 8; ++i) st[i] = (f32x4){0.f, 0.f, 0.f, 0.f};
#pragma unroll
  for (int ks = 0; ks < 4; ++ks) {
    bf16x8 a = *(const bf16x8*)&XT[(wv * 16 + il) * 136 + ks * 32 + fo];
#pragma unroll
    for (int ni = 0; ni < 8; ++ni) {
      bf16x8 bb = *(const bf16x8*)&BdT[(ni * 16 + il) * 136 + ks * 32 + fo];
      st[ni] = __builtin_amdgcn_mfma_f32_16x16x32_bf16(a, bb, st[ni], 0, 0, 0);
    }
  }
  size_t base = ((size_t)(b * NH + h) * NCH + c) * (PD * NSD);
#pragma unroll
  for (int ni = 0; ni < 8; ++ni) {
    int n = ni * 16 + il;
#pragma unroll
    for (int r = 0; r < 4; ++r) {
      int p = wv * 16 + rl + r;
      states16[base + p * NSD + n] = f2bf(st[ni][r]);
    }
  }
}

// ---------------- E2: chunk-state scan (bf16x8 per thread, f32 accum) ----------------
__global__ __launch_bounds__(256) void e2_kernel(const float* __restrict__ acsg,
                                                 const unsigned short* __restrict__ states16,
                                                 unsigned short* __restrict__ prevs) {
  int bid = blockIdx.x;          // (b*128+h)*4 + pg
  int bh = bid >> 2, pg = bid & 3;
  int b = bh >> 7;
  int t = threadIdx.x;
  float S[8];
#pragma unroll
  for (int j = 0; j < 8; ++j) S[j] = 0.f;
  for (int c = 0; c < NCH; ++c) {
    float alast = acsg[(((size_t)((b * NCH + c) * NH) + (bh & 127))) * CHK + (CHK - 1)];
    float dec = __expf(alast);
    size_t base = ((size_t)bh * NCH + c) * (PD * NSD) + (size_t)pg * 2048 + (size_t)t * 8;
    bf16x8 v = *(const bf16x8*)(states16 + base);
    unsigned short o[8];
#pragma unroll
    for (int j = 0; j < 8; ++j) {
      o[j] = f2bf(S[j]);
      S[j] = S[j] * dec + bf2f(((unsigned short*)&v)[j]);
    }
    *(bf16x8*)(prevs + base) = *(bf16x8*)o;
  }
}

// ---------------- E13: fused Y_diag + Y_off + D_res -> yb (bf16 out) ----------------
// phase1's per-wave C fragments saved in registers (cf[kc]) and reused as phase5's
// A-operand (identical coverage) -> no phase4 C reload, 2 fewer barriers.
__global__ __launch_bounds__(512) void e13_kernel(const unsigned short* __restrict__ xbc,
                                                  const float* __restrict__ dtg,
                                                  const float* __restrict__ acsg,
                                                  const unsigned short* __restrict__ prevs,
                                                  const float* __restrict__ Dp,
                                                  unsigned short* __restrict__ ybh) {
  int bid = blockIdx.x;
  int h = bid & 127, c = (bid >> 7) & 15, b = bid >> 11;
  int g = h & 7;
  int row0 = b * SEQ + c * CHK;
  __shared__ __align__(16) char smem[70144];
  unsigned short* Cst = (unsigned short*)smem;            // [128][40] Gm phase
  unsigned short* Bst = (unsigned short*)(smem + 10240);  // [128][40] Gm phase
  unsigned short* Mt = (unsigned short*)smem;             // [128][136]
  unsigned short* XT = (unsigned short*)(smem + 34816);   // [64][136]
  unsigned short* Sp = (unsigned short*)(smem + 52224);   // [64][136]
  float* Acs = (float*)(smem + 69632);                    // [128]
  int tid = threadIdx.x, lane = tid & 63, wv = tid >> 6;  // 8 waves
  int fo = (lane >> 4) * 8, il = lane & 15, rl = (lane >> 4) * 4;
  if (tid < 128) Acs[tid] = acsg[(((size_t)(b * NCH + c) * NH) + h) * CHK + tid];

  // phase1: Gm = C @ B^T ; save per-wave C fragments for phase5
  f32x4 gm[8];
#pragma unroll
  for (int i = 0; i < 8; ++i) gm[i] = (f32x4){0.f, 0.f, 0.f, 0.f};
  bf16x8 cf[4];
  int srow = tid >> 2, scol = (tid & 3) * 8;
#pragma unroll
  for (int kc = 0; kc < 4; ++kc) {
    __syncthreads();
    *(int4*)(Cst + srow * 40 + scol) =
        *(const int4*)(xbc + (size_t)(row0 + srow) * CONV_D + INTER_D + NG * NSD + g * NSD + kc * 32 + scol);
    *(int4*)(Bst + srow * 40 + scol) =
        *(const int4*)(xbc + (size_t)(row0 + srow) * CONV_D + INTER_D + g * NSD + kc * 32 + scol);
    __syncthreads();
    bf16x8 a = *(const bf16x8*)&Cst[(wv * 16 + il) * 40 + fo];
    cf[kc] = a;
#pragma unroll
    for (int ni = 0; ni < 8; ++ni) {
      bf16x8 bb = *(const bf16x8*)&Bst[(ni * 16 + il) * 40 + fo];
      gm[ni] = __builtin_amdgcn_mfma_f32_16x16x32_bf16(a, bb, gm[ni], 0, 0, 0);
    }
  }
  __syncthreads();
  // phase2: masked+decayed M -> Mt; stage XT = (hs*dt)^T; stage Sp = prevs (bf16 copy)
#pragma unroll
  for (int ni = 0; ni < 8; ++ni) {
    int s = ni * 16 + il;
#pragma unroll
    for (int r = 0; r < 4; ++r) {
      int ll = wv * 16 + rl + r;
      float v = (s <= ll) ? gm[ni][r] * __expf(Acs[ll] - Acs[s]) : 0.f;
      Mt[ll * 136 + s] = f2bf(v);
    }
  }
#pragma unroll
  for (int j = 0; j < 2; ++j) {
    int q = tid + j * 512;
    int ll = q >> 3, p0 = (q & 7) * 8;
    int row = row0 + ll;
    float dtv = dtg[(size_t)row * NH + h];
    int4 raw = *(const int4*)(xbc + (size_t)row * CONV_D + h * PD + p0);
    unsigned short* u = (unsigned short*)&raw;
#pragma unroll
    for (int e = 0; e < 8; ++e) XT[(p0 + e) * 136 + ll] = f2bf(bf2f(u[e]) * dtv);
  }
  size_t sbase = ((size_t)(b * NH + h) * NCH + c) * (PD * NSD);
#pragma unroll
  for (int j = 0; j < 2; ++j) {
    int q = tid + j * 512;
    int p = q >> 4, n0 = (q & 15) * 8;
    *(int4*)(Sp + p * 136 + n0) = *(const int4*)(prevs + sbase + p * NSD + n0);
  }
  __syncthreads();
  // phase3: Y_diag = M @ X ; fused phase5: Y_off = cf @ Sp^T (registers, no reload)
  f32x4 yd[4], yo[4];
#pragma unroll
  for (int i = 0; i < 4; ++i) {
    yd[i] = (f32x4){0.f, 0.f, 0.f, 0.f};
    yo[i] = (f32x4){0.f, 0.f, 0.f, 0.f};
  }
#pragma unroll
  for (int ks = 0; ks < 4; ++ks) {
    bf16x8 a = *(const bf16x8*)&Mt[(wv * 16 + il) * 136 + ks * 32 + fo];
#pragma unroll
    for (int pi = 0; pi < 4; ++pi) {
      bf16x8 bb = *(const bf16x8*)&XT[(pi * 16 + il) * 136 + ks * 32 + fo];
      bf16x8 sb = *(const bf16x8*)&Sp[(pi * 16 + il) * 136 + ks * 32 + fo];
      yd[pi] = __builtin_amdgcn_mfma_f32_16x16x32_bf16(a, bb, yd[pi], 0, 0, 0);
      yo[pi] = __builtin_amdgcn_mfma_f32_16x16x32_bf16(cf[ks], sb, yo[pi], 0, 0, 0);
    }
  }
  float dv = Dp[h];
#pragma unroll
  for (int pi = 0; pi < 4; ++pi) {
    int p = pi * 16 + il;
#pragma unroll
    for (int r = 0; r < 4; ++r) {
      int ll = wv * 16 + rl + r;
      int row = row0 + ll;
      float hsv = bf2f(xbc[(size_t)row * CONV_D + h * PD + p]);
      ybh[(size_t)row * INTER_D + h * PD + p] =
          f2bf(yd[pi][r] + yo[pi][r] * __expf(Acs[ll]) + dv * hsv);
    }
  }
}

// ---------------- F: gate silu, grouped RMSNorm (wave-per-group, shuffle-only) ----------------
__global__ __launch_bounds__(256) void fnorm_kernel(const unsigned short* __restrict__ ybh,
                                                    const unsigned short* __restrict__ proj,
                                                    const float* __restrict__ nw,
                                                    unsigned short* __restrict__ normed) {
  int gid = blockIdx.x * 4 + (threadIdx.x >> 6);  // group index 0..32767
  int lane = threadIdx.x & 63;
  int row = gid >> 3, gg = gid & 7;
  int ch = gg * 1024 + lane * 16;
  bf16x8 y0 = *(const bf16x8*)(ybh + (size_t)row * INTER_D + ch);
  bf16x8 y1 = *(const bf16x8*)(ybh + (size_t)row * INTER_D + ch + 8);
  bf16x8 g0 = *(const bf16x8*)(proj + (size_t)row * PROJ_D + ch);
  bf16x8 g1 = *(const bf16x8*)(proj + (size_t)row * PROJ_D + ch + 8);
  float v[16];
  float ss = 0.f;
#pragma unroll
  for (int j = 0; j < 8; ++j) {
    float val = bf2f(((unsigned short*)&y0)[j]);
    float gt = bf2f(((unsigned short*)&g0)[j]);
    val *= gt / (1.f + __expf(-gt));
    v[j] = val; ss += val * val;
  }
#pragma unroll
  for (int j = 0; j < 8; ++j) {
    float val = bf2f(((unsigned short*)&y1)[j]);
    float gt = bf2f(((unsigned short*)&g1)[j]);
    val *= gt / (1.f + __expf(-gt));
    v[8 + j] = val; ss += val * val;
  }
#pragma unroll
  for (int o = 1; o < 64; o <<= 1) ss += __shfl_xor(ss, o, 64);
  float rms = rsqrtf(ss / 1024.f + 1e-5f);
  unsigned short o16[16];
#pragma unroll
  for (int q = 0; q < 4; ++q) {
    float4 nwv = *(const float4*)(nw + ch + q * 4);
    const float* nwp = (const float*)&nwv;
#pragma unroll
    for (int j = 0; j < 4; ++j) o16[q * 4 + j] = f2bf(v[q * 4 + j] * rms * nwp[j]);
  }
  *(int4*)(normed + (size_t)row * INTER_D + ch) = *(int4*)o16;
  *(int4*)(normed + (size_t)row * INTER_D + ch + 8) = *(int4*)(o16 + 8);
}

extern "C" void kernel_launch(void* const* d_in, const int* in_sizes, int n_in,
                              void* d_out, int out_size, void* d_ws, size_t ws_size,
                              hipStream_t stream) {
  (void)in_sizes; (void)n_in; (void)out_size; (void)ws_size;
  const float* hs = (const float*)d_in[0];
  const float* w1 = (const float*)d_in[1];
  const float* cw = (const float*)d_in[2];
  const float* cb = (const float*)d_in[3];
  const float* dtb = (const float*)d_in[4];
  const float* alog = (const float*)d_in[5];
  const float* Dp = (const float*)d_in[6];
  const float* nw = (const float*)d_in[7];
  const float* w2 = (const float*)d_in[8];
  float* out = (float*)d_out;
  char* ws = (char*)d_ws;

  unsigned short* hsb = (unsigned short*)(ws);                 // 33,554,432
  unsigned short* w1b = (unsigned short*)(ws + 33554432);      // 153,092,096 (padded to 18688 rows)
  unsigned short* w2b = (unsigned short*)(ws + 186646528);     // 67,108,864
  unsigned short* proj = (unsigned short*)(ws + 253755392);    // 152,043,520
  unsigned short* xbc = (unsigned short*)(ws + 405798912);     // 83,886,080
  float* dtg = (float*)(ws + 489684992);                       // 2,097,152
  float* acsg = (float*)(ws + 491782144);                      // 2,097,152
  unsigned short* states16 = (unsigned short*)(ws + 493879296);// 67,108,864 (bf16)
  unsigned short* prevs = (unsigned short*)(ws + 560988160);   // 67,108,864 (bf16)
  unsigned short* ybh = (unsigned short*)(ws + 628097024);     // 67,108,864 (bf16)
  unsigned short* normed = (unsigned short*)(ws);              // reuses hsb region (dead)

  cvt_all_kernel<<<dim3(123392), dim3(256), 0, stream>>>(hs, w1, w2, hsb, w1b, w2b);

  gemm256<1><<<dim3(16 * 73), dim3(512), 0, stream>>>(hsb, w1b, proj, nullptr,
                                                      PROJ_D, HIDD, HIDD, 0);
  dtsa_kernel<<<dim3(2048), dim3(256), 0, stream>>>(proj, dtb, dtg);
  dtsb_kernel<<<dim3(32), dim3(128), 0, stream>>>(dtg, alog, acsg);
  conv_kernel<<<dim3(5, 4096), dim3(256), 0, stream>>>(proj, cw, cb, xbc);
  e1b_kernel<<<dim3(4096), dim3(256), 0, stream>>>(xbc, dtg, acsg, states16);
  e2_kernel<<<dim3(1024), dim3(256), 0, stream>>>(acsg, states16, prevs);
  e13_kernel<<<dim3(4096), dim3(512), 0, stream>>>(xbc, dtg, acsg, prevs, Dp, ybh);
  fnorm_kernel<<<dim3(8192), dim3(256), 0, stream>>>(ybh, proj, nw, normed);
  gemm256<0><<<dim3(16 * 16), dim3(512), 0, stream>>>(normed, w2b, nullptr, out,
                                                      HIDD, INTER_D, INTER_D, 0);
}